// Round 1
// baseline (859.815 us; speedup 1.0000x reference)
//
#include <hip/hip_runtime.h>
#include <hip/hip_bf16.h>

#define SEQ    4096
#define NBAT   4
#define NHEAD  8
#define NBH    32
#define DMODEL 512
#define DHEAD  64
#define NLM    256

typedef __attribute__((ext_vector_type(8))) short s8v;
typedef __attribute__((ext_vector_type(4))) float f4v;

__device__ __forceinline__ float b2f(unsigned short u){
  union { unsigned int i; float f; } v; v.i = ((unsigned int)u) << 16; return v.f;
}
__device__ __forceinline__ unsigned short f2b(float f){
  union { float f; unsigned int i; } v; v.f = f;
  unsigned int r = v.i + 0x7fffu + ((v.i >> 16) & 1u);
  return (unsigned short)(r >> 16);
}
__device__ __forceinline__ s8v ldg8(const unsigned short* p){
  return *reinterpret_cast<const s8v*>(p);
}
__device__ __forceinline__ f4v mfma16(s8v a, s8v b, f4v c){
  return __builtin_amdgcn_mfma_f32_16x16x32_bf16(a, b, c, 0, 0, 0);
}
__device__ __forceinline__ f4v zero4(){ f4v z; z[0]=0.f; z[1]=0.f; z[2]=0.f; z[3]=0.f; return z; }

// ---------------- prep: transpose+cast weights, zero denom & w2f ----------------
__global__ void k_prep(const float* __restrict__ wqkv, const float* __restrict__ wout,
                       unsigned short* __restrict__ wqkvT, unsigned short* __restrict__ woutT,
                       unsigned int* __restrict__ denomU, float* __restrict__ w2f){
  int t = blockIdx.x*256 + threadIdx.x;
  if (t == 0) denomU[0] = 0u;
  if (t < 786432){ int kk = t/1536, n = t%1536; wqkvT[(size_t)n*512 + kk] = f2b(wqkv[t]); }
  else { int t2 = t - 786432; if (t2 < 262144){ int kk = t2/512, n = t2%512; woutT[(size_t)n*512 + kk] = f2b(wout[t2]); } }
  if (t < 524288) w2f[t] = 0.f;
}

// ---------------- LayerNorm -> xn bf16 ----------------
__global__ __launch_bounds__(256) void k_ln(const float* __restrict__ x, const float* __restrict__ g,
                                            const float* __restrict__ be, unsigned short* __restrict__ xn){
  int row = blockIdx.x*4 + (threadIdx.x>>6);
  int l = threadIdx.x & 63;
  const float* xr = x + (size_t)row*DMODEL;
  float4 a = *(const float4*)(xr + l*4);
  float4 b = *(const float4*)(xr + 256 + l*4);
  float s = a.x+a.y+a.z+a.w + b.x+b.y+b.z+b.w;
  float q = a.x*a.x+a.y*a.y+a.z*a.z+a.w*a.w + b.x*b.x+b.y*b.y+b.z*b.z+b.w*b.w;
  #pragma unroll
  for (int m=1;m<64;m<<=1){ s += __shfl_xor(s,m); q += __shfl_xor(q,m); }
  float mean = s*(1.f/DMODEL);
  float rstd = rsqrtf(q*(1.f/DMODEL) - mean*mean + 1e-5f);
  int c0 = l*4, c1 = 256 + l*4;
  float av[4] = {a.x,a.y,a.z,a.w}, bv[4] = {b.x,b.y,b.z,b.w};
  ushort4 u0, u1;
  unsigned short* p0 = (unsigned short*)&u0; unsigned short* p1 = (unsigned short*)&u1;
  #pragma unroll
  for (int e=0;e<4;++e){
    p0[e] = f2b((av[e]-mean)*rstd*g[c0+e] + be[c0+e]);
    p1[e] = f2b((bv[e]-mean)*rstd*g[c1+e] + be[c1+e]);
  }
  *(ushort4*)(xn + (size_t)row*DMODEL + c0) = u0;
  *(ushort4*)(xn + (size_t)row*DMODEL + c1) = u1;
}

// ---------------- shared 128x128xK=512 GEMM core (LDS staged, 4 waves) ----------------
__device__ __forceinline__ void gemm512(const unsigned short* __restrict__ A, const unsigned short* __restrict__ B,
                                        int m0, int n0, int t, unsigned short* lA, unsigned short* lB,
                                        f4v acc[4][4]){
  int w = t>>6, l = t&63;
  int wm = (w&1)*64, wn = (w>>1)*64;
  for (int ks=0; ks<16; ++ks){
    #pragma unroll
    for (int it=0; it<2; ++it){
      int cid = it*256 + t; int r = cid>>2, kof = (cid&3)<<3;
      *(s8v*)&lA[r*40 + kof] = ldg8(&A[(size_t)(m0+r)*DMODEL + ks*32 + kof]);
      *(s8v*)&lB[r*40 + kof] = ldg8(&B[(size_t)(n0+r)*DMODEL + ks*32 + kof]);
    }
    __syncthreads();
    s8v af[4], bf[4];
    #pragma unroll
    for (int i=0;i<4;++i) af[i] = *(s8v*)&lA[(wm+i*16+(l&15))*40 + ((l>>4)<<3)];
    #pragma unroll
    for (int j=0;j<4;++j) bf[j] = *(s8v*)&lB[(wn+j*16+(l&15))*40 + ((l>>4)<<3)];
    #pragma unroll
    for (int i=0;i<4;++i)
      #pragma unroll
      for (int j=0;j<4;++j) acc[i][j] = mfma16(af[i], bf[j], acc[i][j]);
    __syncthreads();
  }
}

// ---------------- QKV projection GEMM with scatter epilogue ----------------
__global__ __launch_bounds__(256) void k_gqkv(const unsigned short* __restrict__ xn, const unsigned short* __restrict__ wT,
                                              unsigned short* __restrict__ q, unsigned short* __restrict__ k,
                                              unsigned short* __restrict__ v){
  __shared__ unsigned short lA[128*40], lB[128*40];
  int bid = blockIdx.x; int mblk = bid/12, nblk = bid%12;
  int m0 = mblk*128, n0 = nblk*128;
  int t = threadIdx.x;
  f4v acc[4][4];
  #pragma unroll
  for (int i=0;i<4;++i)
    #pragma unroll
    for (int j=0;j<4;++j) acc[i][j] = zero4();
  gemm512(xn, wT, m0, n0, t, lA, lB, acc);
  int w = t>>6, l = t&63; int wm = (w&1)*64, wn = (w>>1)*64;
  int part = nblk >> 2;                 // 0=q 1=k 2=v (128-col tile lies within one part)
  int coff = (nblk & 3) * 128;
  unsigned short* dst = (part==0) ? q : (part==1) ? k : v;
  float scale = (part==0) ? 0.125f : 1.f;
  #pragma unroll
  for (int i=0;i<4;++i)
  #pragma unroll
  for (int j=0;j<4;++j){
    int colg = coff + wn + j*16 + (l&15);
    int h = colg>>6, c = colg&63;
    #pragma unroll
    for (int r=0;r<4;++r){
      int rowg = m0 + wm + i*16 + ((l>>4)<<2) + r;
      int b = rowg>>12, n = rowg&4095;
      dst[ (((size_t)(b*NHEAD + h))*SEQ + n)*DHEAD + c ] = f2b(acc[i][j][r]*scale);
    }
  }
}

// ---------------- output projection GEMM (+x +bias) ----------------
__global__ __launch_bounds__(256) void k_gout(const unsigned short* __restrict__ ao, const unsigned short* __restrict__ wT,
                                              const float* __restrict__ x, const float* __restrict__ bo,
                                              float* __restrict__ out){
  __shared__ unsigned short lA[128*40], lB[128*40];
  int bid = blockIdx.x; int mblk = bid>>2, nblk = bid&3;
  int m0 = mblk*128, n0 = nblk*128;
  int t = threadIdx.x;
  f4v acc[4][4];
  #pragma unroll
  for (int i=0;i<4;++i)
    #pragma unroll
    for (int j=0;j<4;++j) acc[i][j] = zero4();
  gemm512(ao, wT, m0, n0, t, lA, lB, acc);
  int w = t>>6, l = t&63; int wm = (w&1)*64, wn = (w>>1)*64;
  #pragma unroll
  for (int i=0;i<4;++i)
  #pragma unroll
  for (int j=0;j<4;++j){
    int colg = n0 + wn + j*16 + (l&15);
    #pragma unroll
    for (int r=0;r<4;++r){
      int rowg = m0 + wm + i*16 + ((l>>4)<<2) + r;
      size_t ad = (size_t)rowg*DMODEL + colg;
      out[ad] = acc[i][j][r] + x[ad] + bo[colg];
    }
  }
}

// ---------------- v -> vT transpose ----------------
__global__ __launch_bounds__(256) void k_vT(const unsigned short* __restrict__ v, unsigned short* __restrict__ vT){
  __shared__ unsigned short tile[64][72];
  int bh = blockIdx.x>>6; int n0 = (blockIdx.x&63)*64;
  int t = threadIdx.x;
  #pragma unroll
  for (int it=0; it<4; ++it){
    int cid = it*256 + t; int r = cid>>4, c4 = (cid&15)*4;
    *(ushort4*)&tile[r][c4] = *(const ushort4*)&v[((size_t)bh*SEQ + n0 + r)*DHEAD + c4];
  }
  __syncthreads();
  #pragma unroll
  for (int it=0; it<4; ++it){
    int cid = it*256 + t; int c = cid>>4, n4 = (cid&15)*4;
    ushort4 o;
    o.x = tile[n4+0][c]; o.y = tile[n4+1][c]; o.z = tile[n4+2][c]; o.w = tile[n4+3][c];
    *(ushort4*)&vT[((size_t)bh*DHEAD + c)*SEQ + n0 + n4] = o;
  }
}

// ---------------- landmark means ----------------
__global__ void k_lmk(const unsigned short* __restrict__ q, const unsigned short* __restrict__ k,
                      unsigned short* __restrict__ ql, unsigned short* __restrict__ kl){
  int tg = blockIdx.x*256 + threadIdx.x;   // 524288 total
  int c = tg&63, m = (tg>>6)&255, bh = tg>>14;
  size_t base = ((size_t)bh*SEQ + m*16)*DHEAD + c;
  float sq = 0.f, sk = 0.f;
  #pragma unroll
  for (int j=0;j<16;++j){ sq += b2f(q[base + (size_t)j*DHEAD]); sk += b2f(k[base + (size_t)j*DHEAD]); }
  ql[((size_t)bh*NLM + m)*DHEAD + c] = f2b(sq*(1.f/16.f));
  kl[((size_t)bh*NLM + m)*DHEAD + c] = f2b(sk*(1.f/16.f));
}

// ---------------- attn2 = softmax(q_l k_l^T), store normal+T, colsum->denom ----------------
__global__ __launch_bounds__(512) void k_attn2(const unsigned short* __restrict__ ql, const unsigned short* __restrict__ kl,
                                               unsigned short* __restrict__ a2, unsigned short* __restrict__ a2t,
                                               unsigned int* __restrict__ denomU){
  __shared__ float cs[256];
  int bh = blockIdx.x; int t = threadIdx.x; int w = t>>6, l = t&63;
  const unsigned short* Q = ql + (size_t)bh*NLM*DHEAD;
  const unsigned short* K = kl + (size_t)bh*NLM*DHEAD;
  f4v acc[2][16];
  #pragma unroll
  for (int i=0;i<2;++i)
    #pragma unroll
    for (int j=0;j<16;++j) acc[i][j] = zero4();
  int m0 = w*32;
  #pragma unroll
  for (int ks=0; ks<2; ++ks){
    int kk = ks*32 + ((l>>4)<<3);
    s8v af0 = ldg8(&Q[(size_t)(m0 + (l&15))*DHEAD + kk]);
    s8v af1 = ldg8(&Q[(size_t)(m0 + 16 + (l&15))*DHEAD + kk]);
    #pragma unroll
    for (int j=0;j<16;++j){
      s8v bf = ldg8(&K[(size_t)(j*16 + (l&15))*DHEAD + kk]);
      acc[0][j] = mfma16(af0, bf, acc[0][j]);
      acc[1][j] = mfma16(af1, bf, acc[1][j]);
    }
  }
  #pragma unroll
  for (int i=0;i<2;++i)
  #pragma unroll
  for (int r=0;r<4;++r){
    float mx = -1e30f;
    #pragma unroll
    for (int j=0;j<16;++j) mx = fmaxf(mx, acc[i][j][r]);
    #pragma unroll
    for (int mm=1;mm<16;mm<<=1) mx = fmaxf(mx, __shfl_xor(mx,mm));
    float sm = 0.f;
    #pragma unroll
    for (int j=0;j<16;++j){ float p = __expf(acc[i][j][r]-mx); acc[i][j][r]=p; sm += p; }
    #pragma unroll
    for (int mm=1;mm<16;mm<<=1) sm += __shfl_xor(sm,mm);
    float inv = 1.f/sm;
    #pragma unroll
    for (int j=0;j<16;++j) acc[i][j][r] *= inv;
  }
  for (int e=t; e<256; e+=512) cs[e] = 0.f;
  __syncthreads();
  size_t b0 = (size_t)bh*NLM*NLM;
  #pragma unroll
  for (int i=0;i<2;++i)
  #pragma unroll
  for (int j=0;j<16;++j){
    int col = j*16 + (l&15);
    int rowb = m0 + i*16 + ((l>>4)<<2);
    float csp = 0.f;
    #pragma unroll
    for (int r=0;r<4;++r){
      float p = acc[i][j][r];
      unsigned short pb = f2b(p);
      a2 [b0 + (size_t)(rowb+r)*NLM + col] = pb;
      a2t[b0 + (size_t)col*NLM + rowb + r] = pb;
      csp += p;
    }
    csp += __shfl_xor(csp, 16); csp += __shfl_xor(csp, 32);
    if ((l>>4) == 0) atomicAdd(&cs[col], csp);
  }
  __syncthreads();
  if (t < 256) atomicMax(denomU, __float_as_uint(cs[t]));
}

// ---------------- attn3 softmax rows -> P3 (half of bh) ----------------
__global__ __launch_bounds__(512) void k_attn3p(const unsigned short* __restrict__ ql, const unsigned short* __restrict__ kk_,
                                                unsigned short* __restrict__ p3, int bhoff){
  __shared__ float redm[16][8], reds[16][8];
  int bh = bhoff + (blockIdx.x>>4); int m0 = (blockIdx.x&15)*16;
  int t = threadIdx.x, w = t>>6, l = t&63;
  const unsigned short* Q  = ql  + (size_t)bh*NLM*DHEAD;
  const unsigned short* Kp = kk_ + (size_t)bh*SEQ*DHEAD;
  f4v acc[32];
  #pragma unroll
  for (int j=0;j<32;++j) acc[j] = zero4();
  #pragma unroll
  for (int ks=0; ks<2; ++ks){
    int kof = ks*32 + ((l>>4)<<3);
    s8v af = ldg8(&Q[(size_t)(m0 + (l&15))*DHEAD + kof]);
    #pragma unroll
    for (int j=0;j<32;++j){
      int n = w*512 + j*16 + (l&15);
      s8v bf = ldg8(&Kp[(size_t)n*DHEAD + kof]);
      acc[j] = mfma16(af, bf, acc[j]);
    }
  }
  int g = l>>4;
  float mxr[4];
  #pragma unroll
  for (int r=0;r<4;++r){
    int rl = g*4 + r;
    float mx = -1e30f;
    #pragma unroll
    for (int j=0;j<32;++j) mx = fmaxf(mx, acc[j][r]);
    #pragma unroll
    for (int mm=1;mm<16;mm<<=1) mx = fmaxf(mx, __shfl_xor(mx,mm));
    if ((l&15)==0) redm[rl][w] = mx;
  }
  __syncthreads();
  #pragma unroll
  for (int r=0;r<4;++r){
    int rl = g*4 + r;
    float mx = redm[rl][0];
    #pragma unroll
    for (int ww=1;ww<8;++ww) mx = fmaxf(mx, redm[rl][ww]);
    mxr[r] = mx;
    float sm = 0.f;
    #pragma unroll
    for (int j=0;j<32;++j){ float p = __expf(acc[j][r]-mx); acc[j][r]=p; sm += p; }
    #pragma unroll
    for (int mm=1;mm<16;mm<<=1) sm += __shfl_xor(sm,mm);
    if ((l&15)==0) reds[rl][w] = sm;
  }
  __syncthreads();
  size_t pb = ((size_t)(bh-bhoff)*NLM + m0)*SEQ;
  #pragma unroll
  for (int r=0;r<4;++r){
    int rl = g*4 + r;
    float sm = 0.f;
    #pragma unroll
    for (int ww=0;ww<8;++ww) sm += reds[rl][ww];
    float inv = 1.f/sm;
    #pragma unroll
    for (int j=0;j<32;++j)
      p3[pb + (size_t)rl*SEQ + w*512 + j*16 + (l&15)] = f2b(acc[j][r]*inv);
  }
  (void)mxr;
}

// ---------------- w2 += P3 @ v  (K-split, atomic f32) ----------------
__global__ __launch_bounds__(256) void k_w2(const unsigned short* __restrict__ p3, const unsigned short* __restrict__ vt,
                                            float* __restrict__ w2f, int bhoff){
  int bid = blockIdx.x;
  int kspl = bid & 7, mblk = (bid>>3)&1, bhl = bid>>4;
  int t = threadIdx.x, w = t>>6, l = t&63;
  int m0 = mblk*128 + w*32;
  const unsigned short* P  = p3 + (size_t)bhl*NLM*SEQ;
  const unsigned short* VT = vt + (size_t)(bhoff+bhl)*DHEAD*SEQ;
  f4v acc[2][4];
  #pragma unroll
  for (int i=0;i<2;++i)
    #pragma unroll
    for (int j=0;j<4;++j) acc[i][j] = zero4();
  for (int ks = kspl*16; ks < kspl*16+16; ++ks){
    int kof = ks*32 + ((l>>4)<<3);
    s8v af0 = ldg8(&P[(size_t)(m0 + (l&15))*SEQ + kof]);
    s8v af1 = ldg8(&P[(size_t)(m0 + 16 + (l&15))*SEQ + kof]);
    #pragma unroll
    for (int j=0;j<4;++j){
      s8v bf = ldg8(&VT[(size_t)(j*16 + (l&15))*SEQ + kof]);
      acc[0][j] = mfma16(af0, bf, acc[0][j]);
      acc[1][j] = mfma16(af1, bf, acc[1][j]);
    }
  }
  float* W = w2f + (size_t)(bhoff+bhl)*NLM*DHEAD;
  #pragma unroll
  for (int i=0;i<2;++i)
  #pragma unroll
  for (int j=0;j<4;++j)
    #pragma unroll
    for (int r=0;r<4;++r)
      atomicAdd(&W[(size_t)(m0 + i*16 + ((l>>4)<<2) + r)*DHEAD + j*16 + (l&15)], acc[i][j][r]);
}

// ---------------- w2f -> w2T bf16 ----------------
__global__ void k_w2t(const float* __restrict__ w2f, unsigned short* __restrict__ w2t){
  int tg = blockIdx.x*256 + threadIdx.x;  // 524288
  int m = tg&255, c = (tg>>8)&63, bh = tg>>14;
  w2t[((size_t)bh*DHEAD + c)*NLM + m] = f2b(w2f[((size_t)bh*NLM + m)*DHEAD + c]);
}

// ---------------- depthwise residual conv -> conv_f32 ----------------
__global__ void k_conv(const unsigned short* __restrict__ v, const float* __restrict__ rw, float* __restrict__ cf){
  int tg = blockIdx.x*256 + threadIdx.x;  // 8388608
  int c = tg&63, h = (tg>>6)&7, n = (tg>>9)&4095, b = tg>>21;
  const unsigned short* vb = v + ((size_t)(b*NHEAD + h)*SEQ)*DHEAD + c;
  float s = 0.f;
  #pragma unroll
  for (int o=0;o<33;++o){
    int nn = n + o - 16;
    if (nn >= 0 && nn < SEQ) s += rw[h*33 + o] * b2f(vb[(size_t)nn*DHEAD]);
  }
  cf[tg] = s;
}

// ---------------- batched 64x64-tile GEMM for pinv stages & u ----------------
template<int ALPHA, bool WN, bool WT>
__global__ __launch_bounds__(64) void k_pgemm(
    const unsigned short* __restrict__ A, const unsigned short* __restrict__ BT,
    unsigned short* __restrict__ oN, unsigned short* __restrict__ oT,
    int mt, int nt, long strA, long strBT, long strON, long strOT,
    float sbase, int sdiv, const unsigned int* __restrict__ denomU)
{
  int bid = blockIdx.x;
  int nper = mt*nt;
  int bh = bid/nper, tt = bid%nper;
  int m0 = (tt/nt)*64, n0 = (tt%nt)*64;
  const unsigned short* Ab = A + (size_t)bh*strA;
  const unsigned short* Bb = BT + (size_t)bh*strBT;
  int l = threadIdx.x;
  f4v acc[4][4];
  #pragma unroll
  for (int i=0;i<4;++i)
    #pragma unroll
    for (int j=0;j<4;++j) acc[i][j] = zero4();
  for (int ks=0; ks<8; ++ks){
    int kk = ks*32 + ((l>>4)<<3);
    s8v af[4], bf[4];
    #pragma unroll
    for (int i=0;i<4;++i) af[i] = ldg8(&Ab[(size_t)(m0 + i*16 + (l&15))*256 + kk]);
    #pragma unroll
    for (int j=0;j<4;++j){
      int col = n0 + j*16 + (l&15);
      s8v bv = ldg8(&Bb[(size_t)col*256 + kk]);
      if (ALPHA != 0){
        #pragma unroll
        for (int e=0;e<8;++e){
          short xv = bv[e];
          bv[e] = (kk+e == col) ? (short)f2b((float)ALPHA - b2f((unsigned short)xv))
                                : (short)(xv ^ (short)0x8000);
        }
      }
      bf[j] = bv;
    }
    #pragma unroll
    for (int i=0;i<4;++i)
      #pragma unroll
      for (int j=0;j<4;++j) acc[i][j] = mfma16(af[i], bf[j], acc[i][j]);
  }
  float s = sbase;
  if (sdiv) s /= __uint_as_float(denomU[0]);
  #pragma unroll
  for (int i=0;i<4;++i)
  #pragma unroll
  for (int j=0;j<4;++j){
    int col = n0 + j*16 + (l&15);
    #pragma unroll
    for (int r=0;r<4;++r){
      int row = m0 + i*16 + ((l>>4)<<2) + r;
      unsigned short ob = f2b(acc[i][j][r]*s);
      if constexpr (WN) oN[(size_t)bh*strON + (size_t)row*256 + col] = ob;
      if constexpr (WT) oT[(size_t)bh*strOT + (size_t)col*256 + row] = ob;
    }
  }
}

// ---------------- fused attn1 softmax + (attn1 @ u) + conv add -> ao bf16 ----------------
__global__ __launch_bounds__(256) void k_attn1(const unsigned short* __restrict__ q, const unsigned short* __restrict__ kl,
                                               const unsigned short* __restrict__ ut, const float* __restrict__ cf,
                                               unsigned short* __restrict__ ao){
  __shared__ unsigned short P[128*256];   // 64KB, XOR-swizzled rows
  int bh = blockIdx.x>>5, m0 = (blockIdx.x&31)*128;
  int t = threadIdx.x, w = t>>6, l = t&63;
  const unsigned short* Q = q  + (size_t)bh*SEQ*DHEAD;
  const unsigned short* K = kl + (size_t)bh*NLM*DHEAD;
  f4v acc[2][16];
  #pragma unroll
  for (int i=0;i<2;++i)
    #pragma unroll
    for (int j=0;j<16;++j) acc[i][j] = zero4();
  int wm = w*32;
  #pragma unroll
  for (int ks=0; ks<2; ++ks){
    int kof = ks*32 + ((l>>4)<<3);
    s8v af0 = ldg8(&Q[(size_t)(m0 + wm + (l&15))*DHEAD + kof]);
    s8v af1 = ldg8(&Q[(size_t)(m0 + wm + 16 + (l&15))*DHEAD + kof]);
    #pragma unroll
    for (int j=0;j<16;++j){
      s8v bf = ldg8(&K[(size_t)(j*16 + (l&15))*DHEAD + kof]);
      acc[0][j] = mfma16(af0, bf, acc[0][j]);
      acc[1][j] = mfma16(af1, bf, acc[1][j]);
    }
  }
  #pragma unroll
  for (int i=0;i<2;++i)
  #pragma unroll
  for (int r=0;r<4;++r){
    float mx = -1e30f;
    #pragma unroll
    for (int j=0;j<16;++j) mx = fmaxf(mx, acc[i][j][r]);
    #pragma unroll
    for (int mm=1;mm<16;mm<<=1) mx = fmaxf(mx, __shfl_xor(mx,mm));
    float sm = 0.f;
    #pragma unroll
    for (int j=0;j<16;++j){ float p = __expf(acc[i][j][r]-mx); acc[i][j][r]=p; sm += p; }
    #pragma unroll
    for (int mm=1;mm<16;mm<<=1) sm += __shfl_xor(sm,mm);
    float inv = 1.f/sm;
    #pragma unroll
    for (int j=0;j<16;++j) acc[i][j][r] *= inv;
  }
  #pragma unroll
  for (int i=0;i<2;++i)
  #pragma unroll
  for (int j=0;j<16;++j){
    int col = j*16 + (l&15);
    #pragma unroll
    for (int r=0;r<4;++r){
      int rowl = wm + i*16 + ((l>>4)<<2) + r;
      int byteoff = rowl*512 + ((col*2) ^ ((rowl&7)<<4));
      *(unsigned short*)((char*)P + byteoff) = f2b(acc[i][j][r]);
    }
  }
  __syncthreads();
  f4v a2[2][4];
  #pragma unroll
  for (int i=0;i<2;++i)
    #pragma unroll
    for (int j=0;j<4;++j) a2[i][j] = zero4();
  const unsigned short* U = ut + (size_t)bh*DHEAD*NLM;
  #pragma unroll
  for (int ks=0; ks<8; ++ks){
    int kof = ks*32 + ((l>>4)<<3);
    s8v pf[2];
    #pragma unroll
    for (int i=0;i<2;++i){
      int rowl = wm + i*16 + (l&15);
      pf[i] = *(s8v*)((char*)P + rowl*512 + ((kof*2) ^ ((rowl&7)<<4)));
    }
    #pragma unroll
    for (int j=0;j<4;++j){
      s8v bf = ldg8(&U[(size_t)(j*16 + (l&15))*NLM + kof]);
      a2[0][j] = mfma16(pf[0], bf, a2[0][j]);
      a2[1][j] = mfma16(pf[1], bf, a2[1][j]);
    }
  }
  int b = bh>>3, h = bh&7;
  #pragma unroll
  for (int i=0;i<2;++i)
  #pragma unroll
  for (int j=0;j<4;++j){
    int c = j*16 + (l&15);
    #pragma unroll
    for (int r=0;r<4;++r){
      int n = m0 + wm + i*16 + ((l>>4)<<2) + r;
      size_t ad = ((size_t)(b*SEQ + n))*DMODEL + h*DHEAD + c;
      ao[ad] = f2b(a2[i][j][r] + cf[ad]);
    }
  }
}

// =============================== host ===============================
extern "C" void kernel_launch(void* const* d_in, const int* in_sizes, int n_in,
                              void* d_out, int out_size, void* d_ws, size_t ws_size,
                              hipStream_t stream){
  const float* x    = (const float*)d_in[0];
  const float* lng  = (const float*)d_in[1];
  const float* lnb  = (const float*)d_in[2];
  const float* wqkv = (const float*)d_in[3];
  const float* wout = (const float*)d_in[4];
  const float* bout = (const float*)d_in[5];
  const float* resw = (const float*)d_in[6];
  float* out = (float*)d_out;

  char* ws = (char*)d_ws;
  size_t off = 0;
  auto alloc = [&](size_t bytes)->char*{ char* p = ws + off; off += (bytes + 255) & ~(size_t)255; return p; };

  unsigned short* wqkvT = (unsigned short*)alloc((size_t)1536*512*2);
  unsigned short* woutT = (unsigned short*)alloc((size_t)512*512*2);
  unsigned int*   denomU= (unsigned int*)  alloc(256);
  unsigned short* xn    = (unsigned short*)alloc((size_t)16384*512*2);   // later: zA,zAT,zB,zBT
  unsigned short* zA  = xn;
  unsigned short* zAT = xn + (size_t)1*NBH*NLM*NLM;
  unsigned short* zB  = xn + (size_t)2*NBH*NLM*NLM;
  unsigned short* zBT = xn + (size_t)3*NBH*NLM*NLM;
  unsigned short* q   = (unsigned short*)alloc((size_t)NBH*SEQ*DHEAD*2);
  unsigned short* kb  = (unsigned short*)alloc((size_t)NBH*SEQ*DHEAD*2);
  unsigned short* ao  = kb;  // alias: k dead before attn1
  unsigned short* v   = (unsigned short*)alloc((size_t)NBH*SEQ*DHEAD*2);
  unsigned short* vT  = (unsigned short*)alloc((size_t)NBH*DHEAD*SEQ*2);
  unsigned short* ql  = (unsigned short*)alloc((size_t)NBH*NLM*DHEAD*2);
  unsigned short* kl  = (unsigned short*)alloc((size_t)NBH*NLM*DHEAD*2);
  unsigned short* a2  = (unsigned short*)alloc((size_t)NBH*NLM*NLM*2);
  unsigned short* a2t = (unsigned short*)alloc((size_t)NBH*NLM*NLM*2);
  char* R1            = alloc((size_t)16*NLM*SEQ*2);   // P3 half, then conv_f32 (same size)
  unsigned short* p3  = (unsigned short*)R1;
  float* convf        = (float*)R1;
  unsigned short* xz  = (unsigned short*)alloc((size_t)NBH*NLM*NLM*2);
  unsigned short* xzt = (unsigned short*)alloc((size_t)NBH*NLM*NLM*2);
  unsigned short* ct  = (unsigned short*)alloc((size_t)NBH*NLM*NLM*2);
  unsigned short* dmt = (unsigned short*)alloc((size_t)NBH*NLM*NLM*2);
  float*          w2f = (float*)         alloc((size_t)NBH*NLM*DHEAD*4);
  unsigned short* w2t = (unsigned short*)alloc((size_t)NBH*DHEAD*NLM*2);
  unsigned short* ut  = (unsigned short*)alloc((size_t)NBH*DHEAD*NLM*2);
  (void)ws_size; (void)in_sizes; (void)n_in; (void)out_size;

  k_prep<<<4096,256,0,stream>>>(wqkv, wout, wqkvT, woutT, denomU, w2f);
  k_ln  <<<4096,256,0,stream>>>(x, lng, lnb, xn);
  k_gqkv<<<1536,256,0,stream>>>(xn, wqkvT, q, kb, v);
  k_vT  <<<2048,256,0,stream>>>(v, vT);
  k_lmk <<<2048,256,0,stream>>>(q, kb, ql, kl);
  k_attn2<<<32,512,0,stream>>>(ql, kl, a2, a2t, denomU);
  for (int half=0; half<2; ++half){
    k_attn3p<<<256,512,0,stream>>>(ql, kb, p3, half*16);
    k_w2    <<<256,256,0,stream>>>(p3, vT, w2f, half*16);
  }
  k_w2t <<<2048,256,0,stream>>>(w2f, w2t);
  k_conv<<<32768,256,0,stream>>>(v, resw, convf);

  const long S = 65536L;
  unsigned short* zN_[2] = {zA, zB};
  unsigned short* zT_[2] = {zAT, zBT};
  for (int it = 0; it < 6; ++it){
    const unsigned short* ZT   = (it==0) ? a2  : zT_[(it-1)&1];
    const unsigned short* Zrow = (it==0) ? a2t : zN_[(it-1)&1];
    int sdiv = (it==0) ? 1 : 0;
    k_pgemm<0 ,true ,true ><<<512,64,0,stream>>>(a2,  ZT,  xz, xzt, 4,4, S,S,S,S, 1.0f,  sdiv, denomU);
    k_pgemm<7 ,false,true ><<<512,64,0,stream>>>(xz,  xzt, (unsigned short*)nullptr, ct,  4,4, S,S,0L,S, 1.0f, 0, denomU);
    k_pgemm<15,false,true ><<<512,64,0,stream>>>(xz,  ct,  (unsigned short*)nullptr, dmt, 4,4, S,S,0L,S, 1.0f, 0, denomU);
    k_pgemm<13,true ,true ><<<512,64,0,stream>>>(Zrow,dmt, zN_[it&1], zT_[it&1], 4,4, S,S,S,S, 0.25f, sdiv, denomU);
  }
  // uT = (Z6 @ w2)^T
  k_pgemm<0,false,true><<<128,64,0,stream>>>(zN_[1], w2t, (unsigned short*)nullptr, ut, 4,1, S,16384L,0L,16384L, 1.0f, 0, denomU);

  k_attn1<<<1024,256,0,stream>>>(q, kl, ut, convf, ao);
  k_gout <<<512,256,0,stream>>>(ao, woutT, x, bout, out);
}

// Round 2
// 757.988 us; speedup vs baseline: 1.1343x; 1.1343x over previous
//
#include <hip/hip_runtime.h>
#include <hip/hip_bf16.h>

#define SEQ    4096
#define NBAT   4
#define NHEAD  8
#define NBH    32
#define DMODEL 512
#define DHEAD  64
#define NLM    256

typedef __attribute__((ext_vector_type(8))) short s8v;
typedef __attribute__((ext_vector_type(4))) float f4v;

__device__ __forceinline__ float b2f(unsigned short u){
  union { unsigned int i; float f; } v; v.i = ((unsigned int)u) << 16; return v.f;
}
__device__ __forceinline__ unsigned short f2b(float f){
  union { float f; unsigned int i; } v; v.f = f;
  unsigned int r = v.i + 0x7fffu + ((v.i >> 16) & 1u);
  return (unsigned short)(r >> 16);
}
__device__ __forceinline__ s8v ldg8(const unsigned short* p){
  return *reinterpret_cast<const s8v*>(p);
}
__device__ __forceinline__ f4v mfma16(s8v a, s8v b, f4v c){
  return __builtin_amdgcn_mfma_f32_16x16x32_bf16(a, b, c, 0, 0, 0);
}
__device__ __forceinline__ f4v zero4(){ f4v z; z[0]=0.f; z[1]=0.f; z[2]=0.f; z[3]=0.f; return z; }

// ---------------- prep: transpose+cast weights, zero denom & w2f ----------------
__global__ void k_prep(const float* __restrict__ wqkv, const float* __restrict__ wout,
                       unsigned short* __restrict__ wqkvT, unsigned short* __restrict__ woutT,
                       unsigned int* __restrict__ denomU, float* __restrict__ w2f){
  int t = blockIdx.x*256 + threadIdx.x;
  if (t == 0) denomU[0] = 0u;
  if (t < 786432){ int kk = t/1536, n = t%1536; wqkvT[(size_t)n*512 + kk] = f2b(wqkv[t]); }
  else { int t2 = t - 786432; if (t2 < 262144){ int kk = t2/512, n = t2%512; woutT[(size_t)n*512 + kk] = f2b(wout[t2]); } }
  if (t < 524288) w2f[t] = 0.f;
}

// ---------------- LayerNorm -> xn bf16 ----------------
__global__ __launch_bounds__(256) void k_ln(const float* __restrict__ x, const float* __restrict__ g,
                                            const float* __restrict__ be, unsigned short* __restrict__ xn){
  int row = blockIdx.x*4 + (threadIdx.x>>6);
  int l = threadIdx.x & 63;
  const float* xr = x + (size_t)row*DMODEL;
  float4 a = *(const float4*)(xr + l*4);
  float4 b = *(const float4*)(xr + 256 + l*4);
  float s = a.x+a.y+a.z+a.w + b.x+b.y+b.z+b.w;
  float q = a.x*a.x+a.y*a.y+a.z*a.z+a.w*a.w + b.x*b.x+b.y*b.y+b.z*b.z+b.w*b.w;
  #pragma unroll
  for (int m=1;m<64;m<<=1){ s += __shfl_xor(s,m); q += __shfl_xor(q,m); }
  float mean = s*(1.f/DMODEL);
  float rstd = rsqrtf(q*(1.f/DMODEL) - mean*mean + 1e-5f);
  int c0 = l*4, c1 = 256 + l*4;
  float av[4] = {a.x,a.y,a.z,a.w}, bv[4] = {b.x,b.y,b.z,b.w};
  ushort4 u0, u1;
  unsigned short* p0 = (unsigned short*)&u0; unsigned short* p1 = (unsigned short*)&u1;
  #pragma unroll
  for (int e=0;e<4;++e){
    p0[e] = f2b((av[e]-mean)*rstd*g[c0+e] + be[c0+e]);
    p1[e] = f2b((bv[e]-mean)*rstd*g[c1+e] + be[c1+e]);
  }
  *(ushort4*)(xn + (size_t)row*DMODEL + c0) = u0;
  *(ushort4*)(xn + (size_t)row*DMODEL + c1) = u1;
}

// ---------------- shared 128x128xK=512 GEMM core (LDS staged, 4 waves) ----------------
__device__ __forceinline__ void gemm512(const unsigned short* __restrict__ A, const unsigned short* __restrict__ B,
                                        int m0, int n0, int t, unsigned short* lA, unsigned short* lB,
                                        f4v acc[4][4]){
  int w = t>>6, l = t&63;
  int wm = (w&1)*64, wn = (w>>1)*64;
  for (int ks=0; ks<16; ++ks){
    #pragma unroll
    for (int it=0; it<2; ++it){
      int cid = it*256 + t; int r = cid>>2, kof = (cid&3)<<3;
      *(s8v*)&lA[r*40 + kof] = ldg8(&A[(size_t)(m0+r)*DMODEL + ks*32 + kof]);
      *(s8v*)&lB[r*40 + kof] = ldg8(&B[(size_t)(n0+r)*DMODEL + ks*32 + kof]);
    }
    __syncthreads();
    s8v af[4], bf[4];
    #pragma unroll
    for (int i=0;i<4;++i) af[i] = *(s8v*)&lA[(wm+i*16+(l&15))*40 + ((l>>4)<<3)];
    #pragma unroll
    for (int j=0;j<4;++j) bf[j] = *(s8v*)&lB[(wn+j*16+(l&15))*40 + ((l>>4)<<3)];
    #pragma unroll
    for (int i=0;i<4;++i)
      #pragma unroll
      for (int j=0;j<4;++j) acc[i][j] = mfma16(af[i], bf[j], acc[i][j]);
    __syncthreads();
  }
}

// ---------------- QKV projection GEMM with scatter epilogue ----------------
__global__ __launch_bounds__(256) void k_gqkv(const unsigned short* __restrict__ xn, const unsigned short* __restrict__ wT,
                                              unsigned short* __restrict__ q, unsigned short* __restrict__ k,
                                              unsigned short* __restrict__ v){
  __shared__ unsigned short lA[128*40], lB[128*40];
  int bid = blockIdx.x; int mblk = bid/12, nblk = bid%12;
  int m0 = mblk*128, n0 = nblk*128;
  int t = threadIdx.x;
  f4v acc[4][4];
  #pragma unroll
  for (int i=0;i<4;++i)
    #pragma unroll
    for (int j=0;j<4;++j) acc[i][j] = zero4();
  gemm512(xn, wT, m0, n0, t, lA, lB, acc);
  int w = t>>6, l = t&63; int wm = (w&1)*64, wn = (w>>1)*64;
  int part = nblk >> 2;                 // 0=q 1=k 2=v (128-col tile lies within one part)
  int coff = (nblk & 3) * 128;
  unsigned short* dst = (part==0) ? q : (part==1) ? k : v;
  float scale = (part==0) ? 0.125f : 1.f;
  #pragma unroll
  for (int i=0;i<4;++i)
  #pragma unroll
  for (int j=0;j<4;++j){
    int colg = coff + wn + j*16 + (l&15);
    int h = colg>>6, c = colg&63;
    #pragma unroll
    for (int r=0;r<4;++r){
      int rowg = m0 + wm + i*16 + ((l>>4)<<2) + r;
      int b = rowg>>12, n = rowg&4095;
      dst[ (((size_t)(b*NHEAD + h))*SEQ + n)*DHEAD + c ] = f2b(acc[i][j][r]*scale);
    }
  }
}

// ---------------- output projection GEMM (+x +bias) ----------------
__global__ __launch_bounds__(256) void k_gout(const unsigned short* __restrict__ ao, const unsigned short* __restrict__ wT,
                                              const float* __restrict__ x, const float* __restrict__ bo,
                                              float* __restrict__ out){
  __shared__ unsigned short lA[128*40], lB[128*40];
  int bid = blockIdx.x; int mblk = bid>>2, nblk = bid&3;
  int m0 = mblk*128, n0 = nblk*128;
  int t = threadIdx.x;
  f4v acc[4][4];
  #pragma unroll
  for (int i=0;i<4;++i)
    #pragma unroll
    for (int j=0;j<4;++j) acc[i][j] = zero4();
  gemm512(ao, wT, m0, n0, t, lA, lB, acc);
  int w = t>>6, l = t&63; int wm = (w&1)*64, wn = (w>>1)*64;
  #pragma unroll
  for (int i=0;i<4;++i)
  #pragma unroll
  for (int j=0;j<4;++j){
    int colg = n0 + wn + j*16 + (l&15);
    #pragma unroll
    for (int r=0;r<4;++r){
      int rowg = m0 + wm + i*16 + ((l>>4)<<2) + r;
      size_t ad = (size_t)rowg*DMODEL + colg;
      out[ad] = acc[i][j][r] + x[ad] + bo[colg];
    }
  }
}

// ---------------- v -> vT transpose ----------------
__global__ __launch_bounds__(256) void k_vT(const unsigned short* __restrict__ v, unsigned short* __restrict__ vT){
  __shared__ unsigned short tile[64][72];
  int bh = blockIdx.x>>6; int n0 = (blockIdx.x&63)*64;
  int t = threadIdx.x;
  #pragma unroll
  for (int it=0; it<4; ++it){
    int cid = it*256 + t; int r = cid>>4, c4 = (cid&15)*4;
    *(ushort4*)&tile[r][c4] = *(const ushort4*)&v[((size_t)bh*SEQ + n0 + r)*DHEAD + c4];
  }
  __syncthreads();
  #pragma unroll
  for (int it=0; it<4; ++it){
    int cid = it*256 + t; int c = cid>>4, n4 = (cid&15)*4;
    ushort4 o;
    o.x = tile[n4+0][c]; o.y = tile[n4+1][c]; o.z = tile[n4+2][c]; o.w = tile[n4+3][c];
    *(ushort4*)&vT[((size_t)bh*DHEAD + c)*SEQ + n0 + n4] = o;
  }
}

// ---------------- landmark means ----------------
__global__ void k_lmk(const unsigned short* __restrict__ q, const unsigned short* __restrict__ k,
                      unsigned short* __restrict__ ql, unsigned short* __restrict__ kl){
  int tg = blockIdx.x*256 + threadIdx.x;   // 524288 total
  int c = tg&63, m = (tg>>6)&255, bh = tg>>14;
  size_t base = ((size_t)bh*SEQ + m*16)*DHEAD + c;
  float sq = 0.f, sk = 0.f;
  #pragma unroll
  for (int j=0;j<16;++j){ sq += b2f(q[base + (size_t)j*DHEAD]); sk += b2f(k[base + (size_t)j*DHEAD]); }
  ql[((size_t)bh*NLM + m)*DHEAD + c] = f2b(sq*(1.f/16.f));
  kl[((size_t)bh*NLM + m)*DHEAD + c] = f2b(sk*(1.f/16.f));
}

// ---------------- attn2 = softmax(q_l k_l^T), store normal+T, colsum->denom ----------------
__global__ __launch_bounds__(512) void k_attn2(const unsigned short* __restrict__ ql, const unsigned short* __restrict__ kl,
                                               unsigned short* __restrict__ a2, unsigned short* __restrict__ a2t,
                                               unsigned int* __restrict__ denomU){
  __shared__ float cs[256];
  int bh = blockIdx.x; int t = threadIdx.x; int w = t>>6, l = t&63;
  const unsigned short* Q = ql + (size_t)bh*NLM*DHEAD;
  const unsigned short* K = kl + (size_t)bh*NLM*DHEAD;
  f4v acc[2][16];
  #pragma unroll
  for (int i=0;i<2;++i)
    #pragma unroll
    for (int j=0;j<16;++j) acc[i][j] = zero4();
  int m0 = w*32;
  #pragma unroll
  for (int ks=0; ks<2; ++ks){
    int kk = ks*32 + ((l>>4)<<3);
    s8v af0 = ldg8(&Q[(size_t)(m0 + (l&15))*DHEAD + kk]);
    s8v af1 = ldg8(&Q[(size_t)(m0 + 16 + (l&15))*DHEAD + kk]);
    #pragma unroll
    for (int j=0;j<16;++j){
      s8v bf = ldg8(&K[(size_t)(j*16 + (l&15))*DHEAD + kk]);
      acc[0][j] = mfma16(af0, bf, acc[0][j]);
      acc[1][j] = mfma16(af1, bf, acc[1][j]);
    }
  }
  #pragma unroll
  for (int i=0;i<2;++i)
  #pragma unroll
  for (int r=0;r<4;++r){
    float mx = -1e30f;
    #pragma unroll
    for (int j=0;j<16;++j) mx = fmaxf(mx, acc[i][j][r]);
    #pragma unroll
    for (int mm=1;mm<16;mm<<=1) mx = fmaxf(mx, __shfl_xor(mx,mm));
    float sm = 0.f;
    #pragma unroll
    for (int j=0;j<16;++j){ float p = __expf(acc[i][j][r]-mx); acc[i][j][r]=p; sm += p; }
    #pragma unroll
    for (int mm=1;mm<16;mm<<=1) sm += __shfl_xor(sm,mm);
    float inv = 1.f/sm;
    #pragma unroll
    for (int j=0;j<16;++j) acc[i][j][r] *= inv;
  }
  for (int e=t; e<256; e+=512) cs[e] = 0.f;
  __syncthreads();
  size_t b0 = (size_t)bh*NLM*NLM;
  #pragma unroll
  for (int i=0;i<2;++i)
  #pragma unroll
  for (int j=0;j<16;++j){
    int col = j*16 + (l&15);
    int rowb = m0 + i*16 + ((l>>4)<<2);
    float csp = 0.f;
    #pragma unroll
    for (int r=0;r<4;++r){
      float p = acc[i][j][r];
      unsigned short pb = f2b(p);
      a2 [b0 + (size_t)(rowb+r)*NLM + col] = pb;
      a2t[b0 + (size_t)col*NLM + rowb + r] = pb;
      csp += p;
    }
    csp += __shfl_xor(csp, 16); csp += __shfl_xor(csp, 32);
    if ((l>>4) == 0) atomicAdd(&cs[col], csp);
  }
  __syncthreads();
  if (t < 256) atomicMax(denomU, __float_as_uint(cs[t]));
}

// ---------------- attn3 softmax rows -> P3 (half of bh) ----------------
__global__ __launch_bounds__(512) void k_attn3p(const unsigned short* __restrict__ ql, const unsigned short* __restrict__ kk_,
                                                unsigned short* __restrict__ p3, int bhoff){
  __shared__ float redm[16][8], reds[16][8];
  int bh = bhoff + (blockIdx.x>>4); int m0 = (blockIdx.x&15)*16;
  int t = threadIdx.x, w = t>>6, l = t&63;
  const unsigned short* Q  = ql  + (size_t)bh*NLM*DHEAD;
  const unsigned short* Kp = kk_ + (size_t)bh*SEQ*DHEAD;
  f4v acc[32];
  #pragma unroll
  for (int j=0;j<32;++j) acc[j] = zero4();
  #pragma unroll
  for (int ks=0; ks<2; ++ks){
    int kof = ks*32 + ((l>>4)<<3);
    s8v af = ldg8(&Q[(size_t)(m0 + (l&15))*DHEAD + kof]);
    #pragma unroll
    for (int j=0;j<32;++j){
      int n = w*512 + j*16 + (l&15);
      s8v bf = ldg8(&Kp[(size_t)n*DHEAD + kof]);
      acc[j] = mfma16(af, bf, acc[j]);
    }
  }
  int g = l>>4;
  float mxr[4];
  #pragma unroll
  for (int r=0;r<4;++r){
    int rl = g*4 + r;
    float mx = -1e30f;
    #pragma unroll
    for (int j=0;j<32;++j) mx = fmaxf(mx, acc[j][r]);
    #pragma unroll
    for (int mm=1;mm<16;mm<<=1) mx = fmaxf(mx, __shfl_xor(mx,mm));
    if ((l&15)==0) redm[rl][w] = mx;
  }
  __syncthreads();
  #pragma unroll
  for (int r=0;r<4;++r){
    int rl = g*4 + r;
    float mx = redm[rl][0];
    #pragma unroll
    for (int ww=1;ww<8;++ww) mx = fmaxf(mx, redm[rl][ww]);
    mxr[r] = mx;
    float sm = 0.f;
    #pragma unroll
    for (int j=0;j<32;++j){ float p = __expf(acc[j][r]-mx); acc[j][r]=p; sm += p; }
    #pragma unroll
    for (int mm=1;mm<16;mm<<=1) sm += __shfl_xor(sm,mm);
    if ((l&15)==0) reds[rl][w] = sm;
  }
  __syncthreads();
  size_t pb = ((size_t)(bh-bhoff)*NLM + m0)*SEQ;
  #pragma unroll
  for (int r=0;r<4;++r){
    int rl = g*4 + r;
    float sm = 0.f;
    #pragma unroll
    for (int ww=0;ww<8;++ww) sm += reds[rl][ww];
    float inv = 1.f/sm;
    #pragma unroll
    for (int j=0;j<32;++j)
      p3[pb + (size_t)rl*SEQ + w*512 + j*16 + (l&15)] = f2b(acc[j][r]*inv);
  }
  (void)mxr;
}

// ---------------- w2 += P3 @ v  (K-split, atomic f32) ----------------
__global__ __launch_bounds__(256) void k_w2(const unsigned short* __restrict__ p3, const unsigned short* __restrict__ vt,
                                            float* __restrict__ w2f, int bhoff){
  int bid = blockIdx.x;
  int kspl = bid & 7, mblk = (bid>>3)&1, bhl = bid>>4;
  int t = threadIdx.x, w = t>>6, l = t&63;
  int m0 = mblk*128 + w*32;
  const unsigned short* P  = p3 + (size_t)bhl*NLM*SEQ;
  const unsigned short* VT = vt + (size_t)(bhoff+bhl)*DHEAD*SEQ;
  f4v acc[2][4];
  #pragma unroll
  for (int i=0;i<2;++i)
    #pragma unroll
    for (int j=0;j<4;++j) acc[i][j] = zero4();
  for (int ks = kspl*16; ks < kspl*16+16; ++ks){
    int kof = ks*32 + ((l>>4)<<3);
    s8v af0 = ldg8(&P[(size_t)(m0 + (l&15))*SEQ + kof]);
    s8v af1 = ldg8(&P[(size_t)(m0 + 16 + (l&15))*SEQ + kof]);
    #pragma unroll
    for (int j=0;j<4;++j){
      s8v bf = ldg8(&VT[(size_t)(j*16 + (l&15))*SEQ + kof]);
      acc[0][j] = mfma16(af0, bf, acc[0][j]);
      acc[1][j] = mfma16(af1, bf, acc[1][j]);
    }
  }
  float* W = w2f + (size_t)(bhoff+bhl)*NLM*DHEAD;
  #pragma unroll
  for (int i=0;i<2;++i)
  #pragma unroll
  for (int j=0;j<4;++j)
    #pragma unroll
    for (int r=0;r<4;++r)
      atomicAdd(&W[(size_t)(m0 + i*16 + ((l>>4)<<2) + r)*DHEAD + j*16 + (l&15)], acc[i][j][r]);
}

// ---------------- w2f -> w2T bf16 ----------------
__global__ void k_w2t(const float* __restrict__ w2f, unsigned short* __restrict__ w2t){
  int tg = blockIdx.x*256 + threadIdx.x;  // 524288
  int m = tg&255, c = (tg>>8)&63, bh = tg>>14;
  w2t[((size_t)bh*DHEAD + c)*NLM + m] = f2b(w2f[((size_t)bh*NLM + m)*DHEAD + c]);
}

// ---------------- depthwise residual conv -> cf bf16 ----------------
// 16 outputs/thread: 4 channels (ushort4) x 4 consecutive n, sliding-window reuse.
__global__ __launch_bounds__(256) void k_conv(const unsigned short* __restrict__ v, const float* __restrict__ rw,
                                              unsigned short* __restrict__ cf){
  int bh = blockIdx.x >> 6;           // 32 bh
  int n0 = (blockIdx.x & 63) * 64;    // 64 n per block
  int h = bh & 7, b = bh >> 3;
  int t = threadIdx.x;
  int tx = t & 15, ty = t >> 4;
  int c4 = tx * 4;
  int nb = n0 + ty * 4;               // outputs nb..nb+3
  const unsigned short* vb = v + ((size_t)bh * SEQ) * DHEAD + c4;
  ushort4 val[36];
  #pragma unroll
  for (int i = 0; i < 36; ++i){
    int nn = nb - 16 + i;
    if (nn >= 0 && nn < SEQ) val[i] = *(const ushort4*)(vb + (size_t)nn * DHEAD);
    else { val[i].x = 0; val[i].y = 0; val[i].z = 0; val[i].w = 0; }
  }
  float wgt[33];
  #pragma unroll
  for (int o = 0; o < 33; ++o) wgt[o] = rw[h*33 + o];
  #pragma unroll
  for (int i = 0; i < 4; ++i){
    float s0 = 0.f, s1 = 0.f, s2 = 0.f, s3 = 0.f;
    #pragma unroll
    for (int o = 0; o < 33; ++o){
      ushort4 u = val[i + o];
      float w0 = wgt[o];
      s0 += w0 * b2f(u.x); s1 += w0 * b2f(u.y);
      s2 += w0 * b2f(u.z); s3 += w0 * b2f(u.w);
    }
    ushort4 ov;
    ov.x = f2b(s0); ov.y = f2b(s1); ov.z = f2b(s2); ov.w = f2b(s3);
    size_t ad = ((size_t)b * SEQ + (nb + i)) * DMODEL + h * DHEAD + c4;
    *(ushort4*)(cf + ad) = ov;
  }
}

// ---------------- batched 64x64-tile GEMM for pinv stages & u ----------------
template<int ALPHA, bool WN, bool WT>
__global__ __launch_bounds__(64) void k_pgemm(
    const unsigned short* __restrict__ A, const unsigned short* __restrict__ BT,
    unsigned short* __restrict__ oN, unsigned short* __restrict__ oT,
    int mt, int nt, long strA, long strBT, long strON, long strOT,
    float sbase, int sdiv, const unsigned int* __restrict__ denomU)
{
  int bid = blockIdx.x;
  int nper = mt*nt;
  int bh = bid/nper, tt = bid%nper;
  int m0 = (tt/nt)*64, n0 = (tt%nt)*64;
  const unsigned short* Ab = A + (size_t)bh*strA;
  const unsigned short* Bb = BT + (size_t)bh*strBT;
  int l = threadIdx.x;
  f4v acc[4][4];
  #pragma unroll
  for (int i=0;i<4;++i)
    #pragma unroll
    for (int j=0;j<4;++j) acc[i][j] = zero4();
  for (int ks=0; ks<8; ++ks){
    int kk = ks*32 + ((l>>4)<<3);
    s8v af[4], bf[4];
    #pragma unroll
    for (int i=0;i<4;++i) af[i] = ldg8(&Ab[(size_t)(m0 + i*16 + (l&15))*256 + kk]);
    #pragma unroll
    for (int j=0;j<4;++j){
      int col = n0 + j*16 + (l&15);
      s8v bv = ldg8(&Bb[(size_t)col*256 + kk]);
      if (ALPHA != 0){
        #pragma unroll
        for (int e=0;e<8;++e){
          short xv = bv[e];
          bv[e] = (kk+e == col) ? (short)f2b((float)ALPHA - b2f((unsigned short)xv))
                                : (short)(xv ^ (short)0x8000);
        }
      }
      bf[j] = bv;
    }
    #pragma unroll
    for (int i=0;i<4;++i)
      #pragma unroll
      for (int j=0;j<4;++j) acc[i][j] = mfma16(af[i], bf[j], acc[i][j]);
  }
  float s = sbase;
  if (sdiv) s /= __uint_as_float(denomU[0]);
  #pragma unroll
  for (int i=0;i<4;++i)
  #pragma unroll
  for (int j=0;j<4;++j){
    int col = n0 + j*16 + (l&15);
    #pragma unroll
    for (int r=0;r<4;++r){
      int row = m0 + i*16 + ((l>>4)<<2) + r;
      unsigned short ob = f2b(acc[i][j][r]*s);
      if constexpr (WN) oN[(size_t)bh*strON + (size_t)row*256 + col] = ob;
      if constexpr (WT) oT[(size_t)bh*strOT + (size_t)col*256 + row] = ob;
    }
  }
}

// ---------------- fused attn1 softmax + (attn1 @ u) + conv add -> ao bf16 ----------------
__global__ __launch_bounds__(256) void k_attn1(const unsigned short* __restrict__ q, const unsigned short* __restrict__ kl,
                                               const unsigned short* __restrict__ ut, const unsigned short* __restrict__ cf,
                                               unsigned short* __restrict__ ao){
  __shared__ unsigned short P[128*256];   // 64KB, XOR-swizzled rows
  int bh = blockIdx.x>>5, m0 = (blockIdx.x&31)*128;
  int t = threadIdx.x, w = t>>6, l = t&63;
  const unsigned short* Q = q  + (size_t)bh*SEQ*DHEAD;
  const unsigned short* K = kl + (size_t)bh*NLM*DHEAD;
  f4v acc[2][16];
  #pragma unroll
  for (int i=0;i<2;++i)
    #pragma unroll
    for (int j=0;j<16;++j) acc[i][j] = zero4();
  int wm = w*32;
  #pragma unroll
  for (int ks=0; ks<2; ++ks){
    int kof = ks*32 + ((l>>4)<<3);
    s8v af0 = ldg8(&Q[(size_t)(m0 + wm + (l&15))*DHEAD + kof]);
    s8v af1 = ldg8(&Q[(size_t)(m0 + wm + 16 + (l&15))*DHEAD + kof]);
    #pragma unroll
    for (int j=0;j<16;++j){
      s8v bf = ldg8(&K[(size_t)(j*16 + (l&15))*DHEAD + kof]);
      acc[0][j] = mfma16(af0, bf, acc[0][j]);
      acc[1][j] = mfma16(af1, bf, acc[1][j]);
    }
  }
  #pragma unroll
  for (int i=0;i<2;++i)
  #pragma unroll
  for (int r=0;r<4;++r){
    float mx = -1e30f;
    #pragma unroll
    for (int j=0;j<16;++j) mx = fmaxf(mx, acc[i][j][r]);
    #pragma unroll
    for (int mm=1;mm<16;mm<<=1) mx = fmaxf(mx, __shfl_xor(mx,mm));
    float sm = 0.f;
    #pragma unroll
    for (int j=0;j<16;++j){ float p = __expf(acc[i][j][r]-mx); acc[i][j][r]=p; sm += p; }
    #pragma unroll
    for (int mm=1;mm<16;mm<<=1) sm += __shfl_xor(sm,mm);
    float inv = 1.f/sm;
    #pragma unroll
    for (int j=0;j<16;++j) acc[i][j][r] *= inv;
  }
  #pragma unroll
  for (int i=0;i<2;++i)
  #pragma unroll
  for (int j=0;j<16;++j){
    int col = j*16 + (l&15);
    #pragma unroll
    for (int r=0;r<4;++r){
      int rowl = wm + i*16 + ((l>>4)<<2) + r;
      int byteoff = rowl*512 + ((col*2) ^ ((rowl&7)<<4));
      *(unsigned short*)((char*)P + byteoff) = f2b(acc[i][j][r]);
    }
  }
  __syncthreads();
  f4v a2[2][4];
  #pragma unroll
  for (int i=0;i<2;++i)
    #pragma unroll
    for (int j=0;j<4;++j) a2[i][j] = zero4();
  const unsigned short* U = ut + (size_t)bh*DHEAD*NLM;
  #pragma unroll
  for (int ks=0; ks<8; ++ks){
    int kof = ks*32 + ((l>>4)<<3);
    s8v pf[2];
    #pragma unroll
    for (int i=0;i<2;++i){
      int rowl = wm + i*16 + (l&15);
      pf[i] = *(s8v*)((char*)P + rowl*512 + ((kof*2) ^ ((rowl&7)<<4)));
    }
    #pragma unroll
    for (int j=0;j<4;++j){
      s8v bf = ldg8(&U[(size_t)(j*16 + (l&15))*NLM + kof]);
      a2[0][j] = mfma16(pf[0], bf, a2[0][j]);
      a2[1][j] = mfma16(pf[1], bf, a2[1][j]);
    }
  }
  int b = bh>>3, h = bh&7;
  #pragma unroll
  for (int i=0;i<2;++i)
  #pragma unroll
  for (int j=0;j<4;++j){
    int c = j*16 + (l&15);
    #pragma unroll
    for (int r=0;r<4;++r){
      int n = m0 + wm + i*16 + ((l>>4)<<2) + r;
      size_t ad = ((size_t)(b*SEQ + n))*DMODEL + h*DHEAD + c;
      ao[ad] = f2b(a2[i][j][r] + b2f(cf[ad]));
    }
  }
}

// =============================== host ===============================
extern "C" void kernel_launch(void* const* d_in, const int* in_sizes, int n_in,
                              void* d_out, int out_size, void* d_ws, size_t ws_size,
                              hipStream_t stream){
  const float* x    = (const float*)d_in[0];
  const float* lng  = (const float*)d_in[1];
  const float* lnb  = (const float*)d_in[2];
  const float* wqkv = (const float*)d_in[3];
  const float* wout = (const float*)d_in[4];
  const float* bout = (const float*)d_in[5];
  const float* resw = (const float*)d_in[6];
  float* out = (float*)d_out;

  char* ws = (char*)d_ws;
  size_t off = 0;
  auto alloc = [&](size_t bytes)->char*{ char* p = ws + off; off += (bytes + 255) & ~(size_t)255; return p; };

  unsigned short* wqkvT = (unsigned short*)alloc((size_t)1536*512*2);
  unsigned short* woutT = (unsigned short*)alloc((size_t)512*512*2);
  unsigned int*   denomU= (unsigned int*)  alloc(256);
  unsigned short* xn    = (unsigned short*)alloc((size_t)16384*512*2);   // later: zA,zAT,zB,zBT
  unsigned short* zA  = xn;
  unsigned short* zAT = xn + (size_t)1*NBH*NLM*NLM;
  unsigned short* zB  = xn + (size_t)2*NBH*NLM*NLM;
  unsigned short* zBT = xn + (size_t)3*NBH*NLM*NLM;
  unsigned short* q   = (unsigned short*)alloc((size_t)NBH*SEQ*DHEAD*2);
  unsigned short* kb  = (unsigned short*)alloc((size_t)NBH*SEQ*DHEAD*2);
  unsigned short* ao  = kb;  // alias: k dead before attn1
  unsigned short* v   = (unsigned short*)alloc((size_t)NBH*SEQ*DHEAD*2);
  unsigned short* vT  = (unsigned short*)alloc((size_t)NBH*DHEAD*SEQ*2);
  unsigned short* ql  = (unsigned short*)alloc((size_t)NBH*NLM*DHEAD*2);
  unsigned short* kl  = (unsigned short*)alloc((size_t)NBH*NLM*DHEAD*2);
  unsigned short* a2  = (unsigned short*)alloc((size_t)NBH*NLM*NLM*2);
  unsigned short* a2t = (unsigned short*)alloc((size_t)NBH*NLM*NLM*2);
  char* R1            = alloc((size_t)16*NLM*SEQ*2);   // P3 half, then conv bf16 (same size)
  unsigned short* p3  = (unsigned short*)R1;
  unsigned short* convf = (unsigned short*)R1;
  unsigned short* xz  = (unsigned short*)alloc((size_t)NBH*NLM*NLM*2);
  unsigned short* xzt = (unsigned short*)alloc((size_t)NBH*NLM*NLM*2);
  unsigned short* ct  = (unsigned short*)alloc((size_t)NBH*NLM*NLM*2);
  unsigned short* dmt = (unsigned short*)alloc((size_t)NBH*NLM*NLM*2);
  float*          w2f = (float*)         alloc((size_t)NBH*NLM*DHEAD*4);
  unsigned short* w2t = (unsigned short*)alloc((size_t)NBH*DHEAD*NLM*2);
  unsigned short* ut  = (unsigned short*)alloc((size_t)NBH*DHEAD*NLM*2);
  (void)ws_size; (void)in_sizes; (void)n_in; (void)out_size;

  k_prep<<<4096,256,0,stream>>>(wqkv, wout, wqkvT, woutT, denomU, w2f);
  k_ln  <<<4096,256,0,stream>>>(x, lng, lnb, xn);
  k_gqkv<<<1536,256,0,stream>>>(xn, wqkvT, q, kb, v);
  k_vT  <<<2048,256,0,stream>>>(v, vT);
  k_lmk <<<2048,256,0,stream>>>(q, kb, ql, kl);
  k_attn2<<<32,512,0,stream>>>(ql, kl, a2, a2t, denomU);
  for (int half=0; half<2; ++half){
    k_attn3p<<<256,512,0,stream>>>(ql, kb, p3, half*16);
    k_w2    <<<256,256,0,stream>>>(p3, vT, w2f, half*16);
  }
  k_w2t <<<2048,256,0,stream>>>(w2f, w2t);
  k_conv<<<2048,256,0,stream>>>(v, resw, convf);

  const long S = 65536L;
  unsigned short* zN_[2] = {zA, zB};
  unsigned short* zT_[2] = {zAT, zBT};
  for (int it = 0; it < 6; ++it){
    const unsigned short* ZT   = (it==0) ? a2  : zT_[(it-1)&1];
    const unsigned short* Zrow = (it==0) ? a2t : zN_[(it-1)&1];
    int sdiv = (it==0) ? 1 : 0;
    k_pgemm<0 ,true ,true ><<<512,64,0,stream>>>(a2,  ZT,  xz, xzt, 4,4, S,S,S,S, 1.0f,  sdiv, denomU);
    k_pgemm<7 ,false,true ><<<512,64,0,stream>>>(xz,  xzt, (unsigned short*)nullptr, ct,  4,4, S,S,0L,S, 1.0f, 0, denomU);
    k_pgemm<15,false,true ><<<512,64,0,stream>>>(xz,  ct,  (unsigned short*)nullptr, dmt, 4,4, S,S,0L,S, 1.0f, 0, denomU);
    k_pgemm<13,true ,true ><<<512,64,0,stream>>>(Zrow,dmt, zN_[it&1], zT_[it&1], 4,4, S,S,S,S, 0.25f, sdiv, denomU);
  }
  // uT = (Z6 @ w2)^T
  k_pgemm<0,false,true><<<128,64,0,stream>>>(zN_[1], w2t, (unsigned short*)nullptr, ut, 4,1, S,16384L,0L,16384L, 1.0f, 0, denomU);

  k_attn1<<<1024,256,0,stream>>>(q, kl, ut, convf, ao);
  k_gout <<<512,256,0,stream>>>(ao, woutT, x, bout, out);
}

// Round 3
// 546.291 us; speedup vs baseline: 1.5739x; 1.3875x over previous
//
#include <hip/hip_runtime.h>
#include <hip/hip_bf16.h>

#define SEQ    4096
#define NBAT   4
#define NHEAD  8
#define NBH    32
#define DMODEL 512
#define DHEAD  64
#define NLM    256

typedef __attribute__((ext_vector_type(8))) short s8v;
typedef __attribute__((ext_vector_type(4))) float f4v;

__device__ __forceinline__ float b2f(unsigned short u){
  union { unsigned int i; float f; } v; v.i = ((unsigned int)u) << 16; return v.f;
}
__device__ __forceinline__ unsigned short f2b(float f){
  union { float f; unsigned int i; } v; v.f = f;
  unsigned int r = v.i + 0x7fffu + ((v.i >> 16) & 1u);
  return (unsigned short)(r >> 16);
}
__device__ __forceinline__ s8v ldg8(const unsigned short* p){
  return *reinterpret_cast<const s8v*>(p);
}
__device__ __forceinline__ f4v mfma16(s8v a, s8v b, f4v c){
  return __builtin_amdgcn_mfma_f32_16x16x32_bf16(a, b, c, 0, 0, 0);
}
__device__ __forceinline__ f4v zero4(){ f4v z; z[0]=0.f; z[1]=0.f; z[2]=0.f; z[3]=0.f; return z; }

// ---------------- prep: transpose+cast weights, zero denom & w2f ----------------
__global__ void k_prep(const float* __restrict__ wqkv, const float* __restrict__ wout,
                       unsigned short* __restrict__ wqkvT, unsigned short* __restrict__ woutT,
                       unsigned int* __restrict__ denomU, float* __restrict__ w2f){
  int t = blockIdx.x*256 + threadIdx.x;
  if (t == 0) denomU[0] = 0u;
  if (t < 786432){ int kk = t/1536, n = t%1536; wqkvT[(size_t)n*512 + kk] = f2b(wqkv[t]); }
  else { int t2 = t - 786432; if (t2 < 262144){ int kk = t2/512, n = t2%512; woutT[(size_t)n*512 + kk] = f2b(wout[t2]); } }
  if (t < 524288) w2f[t] = 0.f;
}

// ---------------- LayerNorm -> xn bf16 ----------------
__global__ __launch_bounds__(256) void k_ln(const float* __restrict__ x, const float* __restrict__ g,
                                            const float* __restrict__ be, unsigned short* __restrict__ xn){
  int row = blockIdx.x*4 + (threadIdx.x>>6);
  int l = threadIdx.x & 63;
  const float* xr = x + (size_t)row*DMODEL;
  float4 a = *(const float4*)(xr + l*4);
  float4 b = *(const float4*)(xr + 256 + l*4);
  float s = a.x+a.y+a.z+a.w + b.x+b.y+b.z+b.w;
  float q = a.x*a.x+a.y*a.y+a.z*a.z+a.w*a.w + b.x*b.x+b.y*b.y+b.z*b.z+b.w*b.w;
  #pragma unroll
  for (int m=1;m<64;m<<=1){ s += __shfl_xor(s,m); q += __shfl_xor(q,m); }
  float mean = s*(1.f/DMODEL);
  float rstd = rsqrtf(q*(1.f/DMODEL) - mean*mean + 1e-5f);
  int c0 = l*4, c1 = 256 + l*4;
  float av[4] = {a.x,a.y,a.z,a.w}, bv[4] = {b.x,b.y,b.z,b.w};
  ushort4 u0, u1;
  unsigned short* p0 = (unsigned short*)&u0; unsigned short* p1 = (unsigned short*)&u1;
  #pragma unroll
  for (int e=0;e<4;++e){
    p0[e] = f2b((av[e]-mean)*rstd*g[c0+e] + be[c0+e]);
    p1[e] = f2b((bv[e]-mean)*rstd*g[c1+e] + be[c1+e]);
  }
  *(ushort4*)(xn + (size_t)row*DMODEL + c0) = u0;
  *(ushort4*)(xn + (size_t)row*DMODEL + c1) = u1;
}

// ---------------- shared 128x128xK=512 GEMM core (LDS staged, 4 waves) ----------------
__device__ __forceinline__ void gemm512(const unsigned short* __restrict__ A, const unsigned short* __restrict__ B,
                                        int m0, int n0, int t, unsigned short* lA, unsigned short* lB,
                                        f4v acc[4][4]){
  int w = t>>6, l = t&63;
  int wm = (w&1)*64, wn = (w>>1)*64;
  for (int ks=0; ks<16; ++ks){
    #pragma unroll
    for (int it=0; it<2; ++it){
      int cid = it*256 + t; int r = cid>>2, kof = (cid&3)<<3;
      *(s8v*)&lA[r*40 + kof] = ldg8(&A[(size_t)(m0+r)*DMODEL + ks*32 + kof]);
      *(s8v*)&lB[r*40 + kof] = ldg8(&B[(size_t)(n0+r)*DMODEL + ks*32 + kof]);
    }
    __syncthreads();
    s8v af[4], bf[4];
    #pragma unroll
    for (int i=0;i<4;++i) af[i] = *(s8v*)&lA[(wm+i*16+(l&15))*40 + ((l>>4)<<3)];
    #pragma unroll
    for (int j=0;j<4;++j) bf[j] = *(s8v*)&lB[(wn+j*16+(l&15))*40 + ((l>>4)<<3)];
    #pragma unroll
    for (int i=0;i<4;++i)
      #pragma unroll
      for (int j=0;j<4;++j) acc[i][j] = mfma16(af[i], bf[j], acc[i][j]);
    __syncthreads();
  }
}

// ---------------- QKV projection GEMM with scatter epilogue (+vT store fused) ----------------
__global__ __launch_bounds__(256) void k_gqkv(const unsigned short* __restrict__ xn, const unsigned short* __restrict__ wT,
                                              unsigned short* __restrict__ q, unsigned short* __restrict__ k,
                                              unsigned short* __restrict__ v, unsigned short* __restrict__ vT){
  __shared__ unsigned short lA[128*40], lB[128*40];
  int bid = blockIdx.x; int mblk = bid/12, nblk = bid%12;
  int m0 = mblk*128, n0 = nblk*128;
  int t = threadIdx.x;
  f4v acc[4][4];
  #pragma unroll
  for (int i=0;i<4;++i)
    #pragma unroll
    for (int j=0;j<4;++j) acc[i][j] = zero4();
  gemm512(xn, wT, m0, n0, t, lA, lB, acc);
  int w = t>>6, l = t&63; int wm = (w&1)*64, wn = (w>>1)*64;
  int part = nblk >> 2;                 // 0=q 1=k 2=v
  int coff = (nblk & 3) * 128;
  unsigned short* dst = (part==0) ? q : (part==1) ? k : v;
  float scale = (part==0) ? 0.125f : 1.f;
  #pragma unroll
  for (int i=0;i<4;++i)
  #pragma unroll
  for (int j=0;j<4;++j){
    int colg = coff + wn + j*16 + (l&15);
    int h = colg>>6, c = colg&63;
    #pragma unroll
    for (int r=0;r<4;++r){
      int rowg = m0 + wm + i*16 + ((l>>4)<<2) + r;
      int b = rowg>>12, n = rowg&4095;
      unsigned short val = f2b(acc[i][j][r]*scale);
      dst[ (((size_t)(b*NHEAD + h))*SEQ + n)*DHEAD + c ] = val;
      if (part == 2)
        vT[ (((size_t)(b*NHEAD + h))*DHEAD + c)*SEQ + n ] = val;
    }
  }
}

// ---------------- output projection GEMM (+x +bias) ----------------
__global__ __launch_bounds__(256) void k_gout(const unsigned short* __restrict__ ao, const unsigned short* __restrict__ wT,
                                              const float* __restrict__ x, const float* __restrict__ bo,
                                              float* __restrict__ out){
  __shared__ unsigned short lA[128*40], lB[128*40];
  int bid = blockIdx.x; int mblk = bid>>2, nblk = bid&3;
  int m0 = mblk*128, n0 = nblk*128;
  int t = threadIdx.x;
  f4v acc[4][4];
  #pragma unroll
  for (int i=0;i<4;++i)
    #pragma unroll
    for (int j=0;j<4;++j) acc[i][j] = zero4();
  gemm512(ao, wT, m0, n0, t, lA, lB, acc);
  int w = t>>6, l = t&63; int wm = (w&1)*64, wn = (w>>1)*64;
  #pragma unroll
  for (int i=0;i<4;++i)
  #pragma unroll
  for (int j=0;j<4;++j){
    int colg = n0 + wn + j*16 + (l&15);
    #pragma unroll
    for (int r=0;r<4;++r){
      int rowg = m0 + wm + i*16 + ((l>>4)<<2) + r;
      size_t ad = (size_t)rowg*DMODEL + colg;
      out[ad] = acc[i][j][r] + x[ad] + bo[colg];
    }
  }
}

// ---------------- landmark means (vectorized: 4 ch/thread) ----------------
__global__ void k_lmk(const unsigned short* __restrict__ q, const unsigned short* __restrict__ k,
                      unsigned short* __restrict__ ql, unsigned short* __restrict__ kl){
  int tg = blockIdx.x*256 + threadIdx.x;   // 131072 total
  int c4 = (tg&15)*4, m = (tg>>4)&255, bh = tg>>12;
  const unsigned short* qb = q + ((size_t)bh*SEQ + m*16)*DHEAD + c4;
  const unsigned short* kb = k + ((size_t)bh*SEQ + m*16)*DHEAD + c4;
  float s0=0.f,s1=0.f,s2=0.f,s3=0.f, t0=0.f,t1=0.f,t2=0.f,t3=0.f;
  #pragma unroll
  for (int j=0;j<16;++j){
    ushort4 uq = *(const ushort4*)(qb + (size_t)j*DHEAD);
    ushort4 uk = *(const ushort4*)(kb + (size_t)j*DHEAD);
    s0+=b2f(uq.x); s1+=b2f(uq.y); s2+=b2f(uq.z); s3+=b2f(uq.w);
    t0+=b2f(uk.x); t1+=b2f(uk.y); t2+=b2f(uk.z); t3+=b2f(uk.w);
  }
  ushort4 oq, ok;
  oq.x=f2b(s0*(1.f/16.f)); oq.y=f2b(s1*(1.f/16.f)); oq.z=f2b(s2*(1.f/16.f)); oq.w=f2b(s3*(1.f/16.f));
  ok.x=f2b(t0*(1.f/16.f)); ok.y=f2b(t1*(1.f/16.f)); ok.z=f2b(t2*(1.f/16.f)); ok.w=f2b(t3*(1.f/16.f));
  *(ushort4*)(ql + ((size_t)bh*NLM + m)*DHEAD + c4) = oq;
  *(ushort4*)(kl + ((size_t)bh*NLM + m)*DHEAD + c4) = ok;
}

// ---------------- attn2 = softmax(q_l k_l^T), store normal+T, colsum->denom ----------------
__global__ __launch_bounds__(512) void k_attn2(const unsigned short* __restrict__ ql, const unsigned short* __restrict__ kl,
                                               unsigned short* __restrict__ a2, unsigned short* __restrict__ a2t,
                                               unsigned int* __restrict__ denomU){
  __shared__ float cs[256];
  int bh = blockIdx.x; int t = threadIdx.x; int w = t>>6, l = t&63;
  const unsigned short* Q = ql + (size_t)bh*NLM*DHEAD;
  const unsigned short* K = kl + (size_t)bh*NLM*DHEAD;
  f4v acc[2][16];
  #pragma unroll
  for (int i=0;i<2;++i)
    #pragma unroll
    for (int j=0;j<16;++j) acc[i][j] = zero4();
  int m0 = w*32;
  #pragma unroll
  for (int ks=0; ks<2; ++ks){
    int kk = ks*32 + ((l>>4)<<3);
    s8v af0 = ldg8(&Q[(size_t)(m0 + (l&15))*DHEAD + kk]);
    s8v af1 = ldg8(&Q[(size_t)(m0 + 16 + (l&15))*DHEAD + kk]);
    #pragma unroll
    for (int j=0;j<16;++j){
      s8v bf = ldg8(&K[(size_t)(j*16 + (l&15))*DHEAD + kk]);
      acc[0][j] = mfma16(af0, bf, acc[0][j]);
      acc[1][j] = mfma16(af1, bf, acc[1][j]);
    }
  }
  #pragma unroll
  for (int i=0;i<2;++i)
  #pragma unroll
  for (int r=0;r<4;++r){
    float mx = -1e30f;
    #pragma unroll
    for (int j=0;j<16;++j) mx = fmaxf(mx, acc[i][j][r]);
    #pragma unroll
    for (int mm=1;mm<16;mm<<=1) mx = fmaxf(mx, __shfl_xor(mx,mm));
    float sm = 0.f;
    #pragma unroll
    for (int j=0;j<16;++j){ float p = __expf(acc[i][j][r]-mx); acc[i][j][r]=p; sm += p; }
    #pragma unroll
    for (int mm=1;mm<16;mm<<=1) sm += __shfl_xor(sm,mm);
    float inv = 1.f/sm;
    #pragma unroll
    for (int j=0;j<16;++j) acc[i][j][r] *= inv;
  }
  for (int e=t; e<256; e+=512) cs[e] = 0.f;
  __syncthreads();
  size_t b0 = (size_t)bh*NLM*NLM;
  #pragma unroll
  for (int i=0;i<2;++i)
  #pragma unroll
  for (int j=0;j<16;++j){
    int col = j*16 + (l&15);
    int rowb = m0 + i*16 + ((l>>4)<<2);
    float csp = 0.f;
    #pragma unroll
    for (int r=0;r<4;++r){
      float p = acc[i][j][r];
      unsigned short pb = f2b(p);
      a2 [b0 + (size_t)(rowb+r)*NLM + col] = pb;
      a2t[b0 + (size_t)col*NLM + rowb + r] = pb;
      csp += p;
    }
    csp += __shfl_xor(csp, 16); csp += __shfl_xor(csp, 32);
    if ((l>>4) == 0) atomicAdd(&cs[col], csp);
  }
  __syncthreads();
  if (t < 256) atomicMax(denomU, __float_as_uint(cs[t]));
}

// ---------------- attn3 softmax rows -> P3 (half of bh) ----------------
__global__ __launch_bounds__(512) void k_attn3p(const unsigned short* __restrict__ ql, const unsigned short* __restrict__ kk_,
                                                unsigned short* __restrict__ p3, int bhoff){
  __shared__ float redm[16][8], reds[16][8];
  int bh = bhoff + (blockIdx.x>>4); int m0 = (blockIdx.x&15)*16;
  int t = threadIdx.x, w = t>>6, l = t&63;
  const unsigned short* Q  = ql  + (size_t)bh*NLM*DHEAD;
  const unsigned short* Kp = kk_ + (size_t)bh*SEQ*DHEAD;
  f4v acc[32];
  #pragma unroll
  for (int j=0;j<32;++j) acc[j] = zero4();
  #pragma unroll
  for (int ks=0; ks<2; ++ks){
    int kof = ks*32 + ((l>>4)<<3);
    s8v af = ldg8(&Q[(size_t)(m0 + (l&15))*DHEAD + kof]);
    #pragma unroll
    for (int j=0;j<32;++j){
      int n = w*512 + j*16 + (l&15);
      s8v bf = ldg8(&Kp[(size_t)n*DHEAD + kof]);
      acc[j] = mfma16(af, bf, acc[j]);
    }
  }
  int g = l>>4;
  #pragma unroll
  for (int r=0;r<4;++r){
    int rl = g*4 + r;
    float mx = -1e30f;
    #pragma unroll
    for (int j=0;j<32;++j) mx = fmaxf(mx, acc[j][r]);
    #pragma unroll
    for (int mm=1;mm<16;mm<<=1) mx = fmaxf(mx, __shfl_xor(mx,mm));
    if ((l&15)==0) redm[rl][w] = mx;
  }
  __syncthreads();
  #pragma unroll
  for (int r=0;r<4;++r){
    int rl = g*4 + r;
    float mx = redm[rl][0];
    #pragma unroll
    for (int ww=1;ww<8;++ww) mx = fmaxf(mx, redm[rl][ww]);
    float sm = 0.f;
    #pragma unroll
    for (int j=0;j<32;++j){ float p = __expf(acc[j][r]-mx); acc[j][r]=p; sm += p; }
    #pragma unroll
    for (int mm=1;mm<16;mm<<=1) sm += __shfl_xor(sm,mm);
    if ((l&15)==0) reds[rl][w] = sm;
  }
  __syncthreads();
  size_t pb = ((size_t)(bh-bhoff)*NLM + m0)*SEQ;
  #pragma unroll
  for (int r=0;r<4;++r){
    int rl = g*4 + r;
    float sm = 0.f;
    #pragma unroll
    for (int ww=0;ww<8;++ww) sm += reds[rl][ww];
    float inv = 1.f/sm;
    #pragma unroll
    for (int j=0;j<32;++j)
      p3[pb + (size_t)rl*SEQ + w*512 + j*16 + (l&15)] = f2b(acc[j][r]*inv);
  }
}

// ---------------- w2 += P3 @ v  (K-split, atomic f32) ----------------
__global__ __launch_bounds__(256) void k_w2(const unsigned short* __restrict__ p3, const unsigned short* __restrict__ vt,
                                            float* __restrict__ w2f, int bhoff){
  int bid = blockIdx.x;
  int kspl = bid & 7, mblk = (bid>>3)&1, bhl = bid>>4;
  int t = threadIdx.x, w = t>>6, l = t&63;
  int m0 = mblk*128 + w*32;
  const unsigned short* P  = p3 + (size_t)bhl*NLM*SEQ;
  const unsigned short* VT = vt + (size_t)(bhoff+bhl)*DHEAD*SEQ;
  f4v acc[2][4];
  #pragma unroll
  for (int i=0;i<2;++i)
    #pragma unroll
    for (int j=0;j<4;++j) acc[i][j] = zero4();
  for (int ks = kspl*16; ks < kspl*16+16; ++ks){
    int kof = ks*32 + ((l>>4)<<3);
    s8v af0 = ldg8(&P[(size_t)(m0 + (l&15))*SEQ + kof]);
    s8v af1 = ldg8(&P[(size_t)(m0 + 16 + (l&15))*SEQ + kof]);
    #pragma unroll
    for (int j=0;j<4;++j){
      s8v bf = ldg8(&VT[(size_t)(j*16 + (l&15))*SEQ + kof]);
      acc[0][j] = mfma16(af0, bf, acc[0][j]);
      acc[1][j] = mfma16(af1, bf, acc[1][j]);
    }
  }
  float* W = w2f + (size_t)(bhoff+bhl)*NLM*DHEAD;
  #pragma unroll
  for (int i=0;i<2;++i)
  #pragma unroll
  for (int j=0;j<4;++j)
    #pragma unroll
    for (int r=0;r<4;++r)
      atomicAdd(&W[(size_t)(m0 + i*16 + ((l>>4)<<2) + r)*DHEAD + j*16 + (l&15)], acc[i][j][r]);
}

// ---------------- w2f -> w2T bf16 ----------------
__global__ void k_w2t(const float* __restrict__ w2f, unsigned short* __restrict__ w2t){
  int tg = blockIdx.x*256 + threadIdx.x;  // 524288
  int m = tg&255, c = (tg>>8)&63, bh = tg>>14;
  w2t[((size_t)bh*DHEAD + c)*NLM + m] = f2b(w2f[((size_t)bh*NLM + m)*DHEAD + c]);
}

// ---------------- depthwise residual conv -> cf bf16 ----------------
__global__ __launch_bounds__(256) void k_conv(const unsigned short* __restrict__ v, const float* __restrict__ rw,
                                              unsigned short* __restrict__ cf){
  int bh = blockIdx.x >> 6;
  int n0 = (blockIdx.x & 63) * 64;
  int h = bh & 7, b = bh >> 3;
  int t = threadIdx.x;
  int tx = t & 15, ty = t >> 4;
  int c4 = tx * 4;
  int nb = n0 + ty * 4;
  const unsigned short* vb = v + ((size_t)bh * SEQ) * DHEAD + c4;
  ushort4 val[36];
  #pragma unroll
  for (int i = 0; i < 36; ++i){
    int nn = nb - 16 + i;
    if (nn >= 0 && nn < SEQ) val[i] = *(const ushort4*)(vb + (size_t)nn * DHEAD);
    else { val[i].x = 0; val[i].y = 0; val[i].z = 0; val[i].w = 0; }
  }
  float wgt[33];
  #pragma unroll
  for (int o = 0; o < 33; ++o) wgt[o] = rw[h*33 + o];
  #pragma unroll
  for (int i = 0; i < 4; ++i){
    float s0 = 0.f, s1 = 0.f, s2 = 0.f, s3 = 0.f;
    #pragma unroll
    for (int o = 0; o < 33; ++o){
      ushort4 u = val[i + o];
      float w0 = wgt[o];
      s0 += w0 * b2f(u.x); s1 += w0 * b2f(u.y);
      s2 += w0 * b2f(u.z); s3 += w0 * b2f(u.w);
    }
    ushort4 ov;
    ov.x = f2b(s0); ov.y = f2b(s1); ov.z = f2b(s2); ov.w = f2b(s3);
    size_t ad = ((size_t)b * SEQ + (nb + i)) * DMODEL + h * DHEAD + c4;
    *(ushort4*)(cf + ad) = ov;
  }
}

// ---------------- 64x64x256 single-wave MFMA core ----------------
__device__ __forceinline__ void pcore(const unsigned short* __restrict__ Ab, const unsigned short* __restrict__ Bb,
                                      int m0, int n0, int l, f4v acc[4][4]){
  for (int ks=0; ks<8; ++ks){
    int kk = ks*32 + ((l>>4)<<3);
    s8v af[4], bf[4];
    #pragma unroll
    for (int i=0;i<4;++i) af[i] = ldg8(&Ab[(size_t)(m0 + i*16 + (l&15))*256 + kk]);
    #pragma unroll
    for (int j=0;j<4;++j) bf[j] = ldg8(&Bb[(size_t)(n0 + j*16 + (l&15))*256 + kk]);
    #pragma unroll
    for (int i=0;i<4;++i)
      #pragma unroll
      for (int j=0;j<4;++j) acc[i][j] = mfma16(af[i], bf[j], acc[i][j]);
  }
}

// ---------------- pinv stage 1: xz = a2 @ z (write N+T) ----------------
__global__ __launch_bounds__(64) void k_pg1(const unsigned short* __restrict__ A, const unsigned short* __restrict__ BT,
                                            unsigned short* __restrict__ oN, unsigned short* __restrict__ oT,
                                            int sdiv, const unsigned int* __restrict__ denomU){
  int bid = blockIdx.x;
  int bh = bid>>4, tt = bid&15;
  int m0 = (tt>>2)*64, n0 = (tt&3)*64;
  int l = threadIdx.x;
  const unsigned short* Ab = A + (size_t)bh*65536;
  const unsigned short* Bb = BT + (size_t)bh*65536;
  f4v acc[4][4];
  #pragma unroll
  for (int i=0;i<4;++i)
    #pragma unroll
    for (int j=0;j<4;++j) acc[i][j] = zero4();
  pcore(Ab, Bb, m0, n0, l, acc);
  float s = sdiv ? 1.f/__uint_as_float(denomU[0]) : 1.f;
  #pragma unroll
  for (int i=0;i<4;++i)
  #pragma unroll
  for (int j=0;j<4;++j){
    int col = n0 + j*16 + (l&15);
    #pragma unroll
    for (int r=0;r<4;++r){
      int row = m0 + i*16 + ((l>>4)<<2) + r;
      unsigned short ob = f2b(acc[i][j][r]*s);
      oN[(size_t)bh*65536 + (size_t)row*256 + col] = ob;
      oT[(size_t)bh*65536 + (size_t)col*256 + row] = ob;
    }
  }
}

// ---------------- pinv stage 2 (batched): CT = (7*xz - xz@xz)^T ; PN = z @ xz ----------------
__global__ __launch_bounds__(64) void k_pg2(const unsigned short* __restrict__ xzN, const unsigned short* __restrict__ xzT,
                                            const unsigned short* __restrict__ zsrc,
                                            unsigned short* __restrict__ CT, unsigned short* __restrict__ PN,
                                            int sdiv, const unsigned int* __restrict__ denomU){
  int bid = blockIdx.x;
  int part = bid>>9; bid &= 511;
  int bh = bid>>4, tt = bid&15;
  int m0 = (tt>>2)*64, n0 = (tt&3)*64;
  int l = threadIdx.x;
  const unsigned short* Ab = (part==0 ? xzN : zsrc) + (size_t)bh*65536;
  const unsigned short* Bb = xzT + (size_t)bh*65536;
  f4v acc[4][4];
  #pragma unroll
  for (int i=0;i<4;++i)
    #pragma unroll
    for (int j=0;j<4;++j) acc[i][j] = zero4();
  pcore(Ab, Bb, m0, n0, l, acc);
  if (part == 0){
    #pragma unroll
    for (int i=0;i<4;++i)
    #pragma unroll
    for (int j=0;j<4;++j){
      int col = n0 + j*16 + (l&15);
      #pragma unroll
      for (int r=0;r<4;++r){
        int row = m0 + i*16 + ((l>>4)<<2) + r;
        float xv = b2f(xzN[(size_t)bh*65536 + (size_t)row*256 + col]);
        CT[(size_t)bh*65536 + (size_t)col*256 + row] = f2b(7.f*xv - acc[i][j][r]);
      }
    }
  } else {
    float s = sdiv ? 1.f/__uint_as_float(denomU[0]) : 1.f;
    #pragma unroll
    for (int i=0;i<4;++i)
    #pragma unroll
    for (int j=0;j<4;++j){
      int col = n0 + j*16 + (l&15);
      #pragma unroll
      for (int r=0;r<4;++r){
        int row = m0 + i*16 + ((l>>4)<<2) + r;
        PN[(size_t)bh*65536 + (size_t)row*256 + col] = f2b(acc[i][j][r]*s);
      }
    }
  }
}

// ---------------- pinv stage 3: z' = 0.25*(13 z - 15 P + P@C), write N+T ----------------
__global__ __launch_bounds__(64) void k_pg3(const unsigned short* __restrict__ PN, const unsigned short* __restrict__ CT,
                                            const unsigned short* __restrict__ zsrc,
                                            unsigned short* __restrict__ zN, unsigned short* __restrict__ zT,
                                            int sdiv, const unsigned int* __restrict__ denomU){
  int bid = blockIdx.x;
  int bh = bid>>4, tt = bid&15;
  int m0 = (tt>>2)*64, n0 = (tt&3)*64;
  int l = threadIdx.x;
  const unsigned short* Ab = PN + (size_t)bh*65536;
  const unsigned short* Bb = CT + (size_t)bh*65536;
  f4v acc[4][4];
  #pragma unroll
  for (int i=0;i<4;++i)
    #pragma unroll
    for (int j=0;j<4;++j) acc[i][j] = zero4();
  pcore(Ab, Bb, m0, n0, l, acc);
  float zs = sdiv ? 1.f/__uint_as_float(denomU[0]) : 1.f;
  #pragma unroll
  for (int i=0;i<4;++i)
  #pragma unroll
  for (int j=0;j<4;++j){
    int col = n0 + j*16 + (l&15);
    #pragma unroll
    for (int r=0;r<4;++r){
      int row = m0 + i*16 + ((l>>4)<<2) + r;
      float zv = b2f(zsrc[(size_t)bh*65536 + (size_t)row*256 + col])*zs;
      float pv = b2f(PN  [(size_t)bh*65536 + (size_t)row*256 + col]);
      float res = 0.25f*(13.f*zv - 15.f*pv + acc[i][j][r]);
      unsigned short ob = f2b(res);
      zN[(size_t)bh*65536 + (size_t)row*256 + col] = ob;
      zT[(size_t)bh*65536 + (size_t)col*256 + row] = ob;
    }
  }
}

// ---------------- generic batched 64x64-tile GEMM (used for u = z6 @ w2, store T) ----------------
template<bool WN, bool WT>
__global__ __launch_bounds__(64) void k_pgemm(
    const unsigned short* __restrict__ A, const unsigned short* __restrict__ BT,
    unsigned short* __restrict__ oN, unsigned short* __restrict__ oT,
    int mt, int nt, long strA, long strBT, long strON, long strOT)
{
  int bid = blockIdx.x;
  int nper = mt*nt;
  int bh = bid/nper, tt = bid%nper;
  int m0 = (tt/nt)*64, n0 = (tt%nt)*64;
  const unsigned short* Ab = A + (size_t)bh*strA;
  const unsigned short* Bb = BT + (size_t)bh*strBT;
  int l = threadIdx.x;
  f4v acc[4][4];
  #pragma unroll
  for (int i=0;i<4;++i)
    #pragma unroll
    for (int j=0;j<4;++j) acc[i][j] = zero4();
  pcore(Ab, Bb, m0, n0, l, acc);
  #pragma unroll
  for (int i=0;i<4;++i)
  #pragma unroll
  for (int j=0;j<4;++j){
    int col = n0 + j*16 + (l&15);
    #pragma unroll
    for (int r=0;r<4;++r){
      int row = m0 + i*16 + ((l>>4)<<2) + r;
      unsigned short ob = f2b(acc[i][j][r]);
      if constexpr (WN) oN[(size_t)bh*strON + (size_t)row*256 + col] = ob;
      if constexpr (WT) oT[(size_t)bh*strOT + (size_t)col*256 + row] = ob;
    }
  }
}

// ---------------- fused attn1: swapped QK^T, in-register softmax, shuffle P->A frags, @u, +conv ----------------
__global__ __launch_bounds__(256) void k_attn1(const unsigned short* __restrict__ qb, const unsigned short* __restrict__ kl,
                                               const unsigned short* __restrict__ ut, const unsigned short* __restrict__ cf,
                                               unsigned short* __restrict__ ao){
  int bh = blockIdx.x>>6;
  int t = threadIdx.x, w = t>>6, l = t&63;
  int q0 = ((blockIdx.x&63)<<6) + (w<<4);   // 16 q-rows per wave
  int g = l>>4, qi = l&15;
  const unsigned short* Q = qb + (size_t)bh*SEQ*DHEAD;
  const unsigned short* K = kl + (size_t)bh*NLM*DHEAD;
  // swapped QK^T: acc[j] = K_l[16j..16j+16) x Q[q0..q0+16) ; lane holds P[q0+qi, m=16j+4g+r]
  f4v acc[16];
  #pragma unroll
  for (int j=0;j<16;++j) acc[j] = zero4();
  #pragma unroll
  for (int ks=0;ks<2;++ks){
    int kk = ks*32 + g*8;
    s8v bq = ldg8(&Q[(size_t)(q0+qi)*DHEAD + kk]);
    #pragma unroll
    for (int j=0;j<16;++j){
      s8v ak = ldg8(&K[(size_t)(j*16+qi)*DHEAD + kk]);
      acc[j] = mfma16(ak, bq, acc[j]);
    }
  }
  // in-register softmax over 256 (lane-local 64 + 2 shuffles across g-groups)
  float mx = -1e30f;
  #pragma unroll
  for (int j=0;j<16;++j)
    mx = fmaxf(mx, fmaxf(fmaxf(acc[j][0],acc[j][1]), fmaxf(acc[j][2],acc[j][3])));
  mx = fmaxf(mx, __shfl_xor(mx,16));
  mx = fmaxf(mx, __shfl_xor(mx,32));
  float sm = 0.f;
  #pragma unroll
  for (int j=0;j<16;++j)
    #pragma unroll
    for (int r=0;r<4;++r){ float p = __expf(acc[j][r]-mx); acc[j][r]=p; sm += p; }
  sm += __shfl_xor(sm,16); sm += __shfl_xor(sm,32);
  float inv = 1.f/sm;
  // pack P to bf16 pairs: pku[2j+h] = {r=2h, r=2h+1}
  unsigned int pku[32];
  #pragma unroll
  for (int j=0;j<16;++j){
    pku[2*j+0] = (unsigned int)f2b(acc[j][0]*inv) | ((unsigned int)f2b(acc[j][1]*inv)<<16);
    pku[2*j+1] = (unsigned int)f2b(acc[j][2]*inv) | ((unsigned int)f2b(acc[j][3]*inv)<<16);
  }
  // PV: out[q, c] = sum_m P[q,m] ut[c,m]
  const unsigned short* U = ut + (size_t)bh*DHEAD*NLM;
  f4v oacc[4];
  #pragma unroll
  for (int j=0;j<4;++j) oacc[j] = zero4();
  int sl0 = ((g&1)*2)*16 + qi;
  int jsel = g>>1;
  #pragma unroll
  for (int ks=0;ks<8;++ks){
    unsigned int w0a = (unsigned int)__shfl((int)pku[4*ks+0], sl0, 64);
    unsigned int w1a = (unsigned int)__shfl((int)pku[4*ks+1], sl0, 64);
    unsigned int w0b = (unsigned int)__shfl((int)pku[4*ks+2], sl0, 64);
    unsigned int w1b = (unsigned int)__shfl((int)pku[4*ks+3], sl0, 64);
    unsigned int w2a = (unsigned int)__shfl((int)pku[4*ks+0], sl0+16, 64);
    unsigned int w3a = (unsigned int)__shfl((int)pku[4*ks+1], sl0+16, 64);
    unsigned int w2b = (unsigned int)__shfl((int)pku[4*ks+2], sl0+16, 64);
    unsigned int w3b = (unsigned int)__shfl((int)pku[4*ks+3], sl0+16, 64);
    unsigned int wv0 = jsel ? w0b : w0a;
    unsigned int wv1 = jsel ? w1b : w1a;
    unsigned int wv2 = jsel ? w2b : w2a;
    unsigned int wv3 = jsel ? w3b : w3a;
    s8v af;
    af[0] = (short)(wv0&0xffff); af[1] = (short)(wv0>>16);
    af[2] = (short)(wv1&0xffff); af[3] = (short)(wv1>>16);
    af[4] = (short)(wv2&0xffff); af[5] = (short)(wv2>>16);
    af[6] = (short)(wv3&0xffff); af[7] = (short)(wv3>>16);
    int mk = ks*32 + g*8;
    #pragma unroll
    for (int j=0;j<4;++j){
      s8v bu = ldg8(&U[(size_t)(j*16+qi)*NLM + mk]);
      oacc[j] = mfma16(af, bu, oacc[j]);
    }
  }
  int b = bh>>3, h = bh&7;
  #pragma unroll
  for (int j=0;j<4;++j){
    int c = j*16 + qi;
    #pragma unroll
    for (int r=0;r<4;++r){
      int n = q0 + g*4 + r;
      size_t ad = ((size_t)(b*SEQ + n))*DMODEL + h*DHEAD + c;
      ao[ad] = f2b(oacc[j][r] + b2f(cf[ad]));
    }
  }
}

// =============================== host ===============================
extern "C" void kernel_launch(void* const* d_in, const int* in_sizes, int n_in,
                              void* d_out, int out_size, void* d_ws, size_t ws_size,
                              hipStream_t stream){
  const float* x    = (const float*)d_in[0];
  const float* lng  = (const float*)d_in[1];
  const float* lnb  = (const float*)d_in[2];
  const float* wqkv = (const float*)d_in[3];
  const float* wout = (const float*)d_in[4];
  const float* bout = (const float*)d_in[5];
  const float* resw = (const float*)d_in[6];
  float* out = (float*)d_out;

  char* ws = (char*)d_ws;
  size_t off = 0;
  auto alloc = [&](size_t bytes)->char*{ char* p = ws + off; off += (bytes + 255) & ~(size_t)255; return p; };

  unsigned short* wqkvT = (unsigned short*)alloc((size_t)1536*512*2);
  unsigned short* woutT = (unsigned short*)alloc((size_t)512*512*2);
  unsigned int*   denomU= (unsigned int*)  alloc(256);
  unsigned short* xn    = (unsigned short*)alloc((size_t)16384*512*2);   // later: zA,zAT,zB,zBT
  unsigned short* zA  = xn;
  unsigned short* zAT = xn + (size_t)1*NBH*NLM*NLM;
  unsigned short* zB  = xn + (size_t)2*NBH*NLM*NLM;
  unsigned short* zBT = xn + (size_t)3*NBH*NLM*NLM;
  unsigned short* q   = (unsigned short*)alloc((size_t)NBH*SEQ*DHEAD*2);
  unsigned short* kb  = (unsigned short*)alloc((size_t)NBH*SEQ*DHEAD*2);
  unsigned short* ao  = kb;  // alias: k dead before attn1
  unsigned short* v   = (unsigned short*)alloc((size_t)NBH*SEQ*DHEAD*2);
  unsigned short* vT  = (unsigned short*)alloc((size_t)NBH*DHEAD*SEQ*2);
  unsigned short* ql  = (unsigned short*)alloc((size_t)NBH*NLM*DHEAD*2);
  unsigned short* kl  = (unsigned short*)alloc((size_t)NBH*NLM*DHEAD*2);
  unsigned short* a2  = (unsigned short*)alloc((size_t)NBH*NLM*NLM*2);
  unsigned short* a2t = (unsigned short*)alloc((size_t)NBH*NLM*NLM*2);
  char* R1            = alloc((size_t)16*NLM*SEQ*2);   // P3 half, then conv bf16
  unsigned short* p3  = (unsigned short*)R1;
  unsigned short* convf = (unsigned short*)R1;
  unsigned short* xz  = (unsigned short*)alloc((size_t)NBH*NLM*NLM*2);
  unsigned short* xzt = (unsigned short*)alloc((size_t)NBH*NLM*NLM*2);
  unsigned short* pn  = (unsigned short*)alloc((size_t)NBH*NLM*NLM*2);
  unsigned short* ctb = (unsigned short*)alloc((size_t)NBH*NLM*NLM*2);
  float*          w2f = (float*)         alloc((size_t)NBH*NLM*DHEAD*4);
  unsigned short* w2t = (unsigned short*)alloc((size_t)NBH*DHEAD*NLM*2);
  unsigned short* ut  = (unsigned short*)alloc((size_t)NBH*DHEAD*NLM*2);
  (void)ws_size; (void)in_sizes; (void)n_in; (void)out_size;

  k_prep<<<4096,256,0,stream>>>(wqkv, wout, wqkvT, woutT, denomU, w2f);
  k_ln  <<<4096,256,0,stream>>>(x, lng, lnb, xn);
  k_gqkv<<<1536,256,0,stream>>>(xn, wqkvT, q, kb, v, vT);
  k_lmk <<<512,256,0,stream>>>(q, kb, ql, kl);
  k_attn2<<<32,512,0,stream>>>(ql, kl, a2, a2t, denomU);
  for (int half=0; half<2; ++half){
    k_attn3p<<<256,512,0,stream>>>(ql, kb, p3, half*16);
    k_w2    <<<256,256,0,stream>>>(p3, vT, w2f, half*16);
  }
  k_w2t <<<2048,256,0,stream>>>(w2f, w2t);
  k_conv<<<2048,256,0,stream>>>(v, resw, convf);

  unsigned short* zN_[2] = {zA, zB};
  unsigned short* zT_[2] = {zAT, zBT};
  for (int it = 0; it < 6; ++it){
    const unsigned short* BT   = (it==0) ? a2  : zT_[(it-1)&1];   // B = z (stored ^T)
    const unsigned short* zsrc = (it==0) ? a2t : zN_[(it-1)&1];   // z row-major
    int sdiv = (it==0) ? 1 : 0;
    k_pg1<<<512 ,64,0,stream>>>(a2, BT, xz, xzt, sdiv, denomU);
    k_pg2<<<1024,64,0,stream>>>(xz, xzt, zsrc, ctb, pn, sdiv, denomU);
    k_pg3<<<512 ,64,0,stream>>>(pn, ctb, zsrc, zN_[it&1], zT_[it&1], sdiv, denomU);
  }
  // uT = (Z6 @ w2)^T
  k_pgemm<false,true><<<128,64,0,stream>>>(zN_[1], w2t, (unsigned short*)nullptr, ut, 4,1, 65536L,16384L,0L,16384L);

  k_attn1<<<2048,256,0,stream>>>(q, kl, ut, convf, ao);
  k_gout <<<512,256,0,stream>>>(ao, woutT, x, bout, out);
}